// Round 1
// baseline (1419.753 us; speedup 1.0000x reference)
//
#include <hip/hip_runtime.h>
#include <hip/hip_bf16.h>
#include <math.h>

#define B_   8
#define L_   16384
#define D_   256
#define H_   8
#define DFF_ 1024
#define KSEL 1000
#define NTOK (B_*KSEL)   // 8000
#define NALL (B_*L_)     // 131072
#define HD_  32
#define NP_  16

typedef float f32x4 __attribute__((ext_vector_type(4)));
typedef short s16x8 __attribute__((ext_vector_type(8)));
typedef unsigned short u16x8 __attribute__((ext_vector_type(8)));

static __device__ __forceinline__ unsigned short f2bf(float f) {
  unsigned u = __float_as_uint(f);
  u += 0x7FFFu + ((u >> 16) & 1u);       // RNE
  return (unsigned short)(u >> 16);
}
static __device__ __forceinline__ float bf2f(unsigned short h) {
  return __uint_as_float(((unsigned)h) << 16);
}
static __device__ __forceinline__ f32x4 mfma_bf16(s16x8 a, s16x8 b, f32x4 c) {
  return __builtin_amdgcn_mfma_f32_16x16x32_bf16(a, b, c, 0, 0, 0);
}

// ---------------- weight prep: f32 -> bf16, transposed to [n][k] ----------------
__global__ void prep_weights(const float* Wqkv, const float* Wo,
                             const float* W1, const float* W2,
                             unsigned short* Wqkvt, unsigned short* Wot,
                             unsigned short* W1t, unsigned short* W2t) {
  int tid = blockIdx.x * blockDim.x + threadIdx.x;
  int stride = gridDim.x * blockDim.x;
  for (int i = tid; i < 768*256; i += stride) { int n = i >> 8, k = i & 255; Wqkvt[i] = f2bf(Wqkv[k*768 + n]); }
  for (int i = tid; i < 256*256; i += stride) { int n = i >> 8, k = i & 255; Wot[i]   = f2bf(Wo[k*256 + n]); }
  for (int i = tid; i < 1024*256; i += stride){ int n = i >> 8, k = i & 255; W1t[i]  = f2bf(W1[k*1024 + n]); }
  for (int i = tid; i < 256*1024; i += stride){ int n = i >> 10, k = i & 1023; W2t[i] = f2bf(W2[k*256 + n]); }
}

// ---------------- per-batch top-K (deterministic) ----------------
__global__ __launch_bounds__(1024) void topk_kernel(const float* es, const float* ss, int* out_idx) {
  __shared__ unsigned keys[L_];
  __shared__ unsigned cnt_s;
  __shared__ int wave_cnt[16];
  __shared__ int base_s;
  int b = blockIdx.x;
  int t = threadIdx.x;
  int base = b * L_;
  for (int i = t; i < L_; i += 1024) {
    float f = es[base + i] + ss[base + i];
    unsigned u = __float_as_uint(f);
    u = (u & 0x80000000u) ? ~u : (u | 0x80000000u);   // sortable
    keys[i] = u;
  }
  __syncthreads();
  // bitwise search: max v with count(>=v) >= K  ->  v = K-th largest key
  unsigned v = 0;
  for (int bit = 31; bit >= 0; --bit) {
    unsigned cand = v | (1u << bit);
    if (t == 0) cnt_s = 0;
    __syncthreads();
    int c = 0;
    for (int i = t; i < L_; i += 1024) c += (keys[i] >= cand) ? 1 : 0;
    for (int m = 1; m < 64; m <<= 1) c += __shfl_xor(c, m);
    if ((t & 63) == 0) atomicAdd(&cnt_s, (unsigned)c);
    __syncthreads();
    if (cnt_s >= (unsigned)KSEL) v = cand;
    __syncthreads();
  }
  // deterministic index-ordered compaction of keys > v
  if (t == 0) base_s = 0;
  __syncthreads();
  int lane = t & 63, w = t >> 6;
  for (int c0 = 0; c0 < L_; c0 += 1024) {
    int i = c0 + t;
    bool pred = keys[i] > v;
    unsigned long long mask = __ballot(pred);
    if (lane == 0) wave_cnt[w] = __popcll(mask);
    __syncthreads();
    int wbase = base_s;
    for (int j = 0; j < w; ++j) wbase += wave_cnt[j];
    if (pred) {
      int pos = wbase + __popcll(mask & ((1ull << lane) - 1ull));
      out_idx[b*KSEL + pos] = base + i;
    }
    __syncthreads();
    if (t == 0) { int tot = 0; for (int j = 0; j < 16; ++j) tot += wave_cnt[j]; base_s += tot; }
    __syncthreads();
  }
  if (t == 0) {   // fill ties (usually exactly 1 element)
    int cnt = base_s;
    for (int i = 0; i < L_ && cnt < KSEL; ++i)
      if (keys[i] == v) { out_idx[b*KSEL + cnt] = base + i; cnt++; }
  }
}

// ---------------- gather + LN1 + rope cos/sin tables ----------------
__global__ __launch_bounds__(256) void gather_ln_rope(
    const float* queries, const int* idx, const int* spat, const int* shapes,
    const float* g1, const float* b1ln, unsigned short* h, float* cosb, float* sinb) {
  int tok = blockIdx.x;
  int t = threadIdx.x;
  int gidx = idx[tok];
  float x = queries[(size_t)gidx * D_ + t];
  float s1 = x, s2 = x * x;
  for (int m = 1; m < 64; m <<= 1) { s1 += __shfl_xor(s1, m); s2 += __shfl_xor(s2, m); }
  __shared__ float p1[4], p2[4];
  int w = t >> 6;
  if ((t & 63) == 0) { p1[w] = s1; p2[w] = s2; }
  __syncthreads();
  float tot  = p1[0] + p1[1] + p1[2] + p1[3];
  float tot2 = p2[0] + p2[1] + p2[2] + p2[3];
  float mu = tot / D_;
  float var = tot2 / D_ - mu * mu;
  float rs = 1.0f / sqrtf(var + 1e-5f);
  h[(size_t)tok * D_ + t] = f2bf((x - mu) * rs * g1[t] + b1ln[t]);
  if (t < NP_) {
    int yy = spat[1*(size_t)NALL + gidx];
    int xx = spat[2*(size_t)NALL + gidx];
    int lv = spat[3*(size_t)NALL + gidx];
    float ang;
    if (t < 6) {
      float sc = (float)shapes[0] / (float)shapes[lv*2+0];
      ang = (float)yy * sc * powf(100.0f, -(float)t / 6.0f);
    } else if (t < 12) {
      float sc = (float)shapes[1] / (float)shapes[lv*2+1];
      ang = (float)xx * sc * powf(100.0f, -(float)(t-6) / 6.0f);
    } else {
      ang = (float)lv * powf(10.0f, -(float)(t-12) / 4.0f);
    }
    cosb[tok*NP_ + t] = cosf(ang);
    sinb[tok*NP_ + t] = sinf(ang);
  }
}

// ---------------- qkv GEMM: (8000x256) @ Wqkv -> q/k/v head-arranged bf16 ----------------
__global__ __launch_bounds__(256) void qkv_gemm(
    const unsigned short* h, const unsigned short* Wt,
    unsigned short* qh, unsigned short* kh, unsigned short* vh) {
  __shared__ unsigned short a_lds[64][264];
  int m0 = blockIdx.y * 64;
  int n0 = blockIdx.x * 128;
  int t = threadIdx.x, lane = t & 63, w = t >> 6;
  int lm = lane & 15, lg = lane >> 4;
  for (int it = 0; it < 8; ++it) {
    int c = it*256 + t;
    int row = c >> 5, off = (c & 31) * 8;
    *(uint4*)&a_lds[row][off] = *(const uint4*)&h[(size_t)(m0+row)*D_ + off];
  }
  __syncthreads();
  f32x4 acc[8];
#pragma unroll
  for (int i = 0; i < 8; ++i) acc[i] = (f32x4){0.f,0.f,0.f,0.f};
#pragma unroll
  for (int ks = 0; ks < 8; ++ks) {
    s16x8 a = *(const s16x8*)&a_lds[w*16 + lm][ks*32 + lg*8];
#pragma unroll
    for (int nt = 0; nt < 8; ++nt) {
      s16x8 bb = *(const s16x8*)&Wt[(size_t)(n0 + nt*16 + lm)*D_ + ks*32 + lg*8];
      acc[nt] = mfma_bf16(a, bb, acc[nt]);
    }
  }
#pragma unroll
  for (int i = 0; i < 4; ++i) {
    int row = w*16 + lg*4 + i;
    int tok = m0 + row;
    int b = tok / 1000, tk = tok - b*1000;
#pragma unroll
    for (int nt = 0; nt < 8; ++nt) {
      int col = n0 + nt*16 + lm;
      int part = col >> 8;
      int within = col & 255;
      int head = within >> 5, d = within & 31;
      unsigned short* dst = part == 0 ? qh : (part == 1 ? kh : vh);
      dst[(size_t)((b*H_ + head)*1000 + tk)*HD_ + d] = f2bf(acc[nt][i]);
    }
  }
}

// ---------------- flash attention per (b,h), rope applied at operand load ----------------
__global__ __launch_bounds__(256) void attn_kernel(
    const unsigned short* qh, const unsigned short* kh, const unsigned short* vh,
    const float* cosb, const float* sinb, unsigned short* obuf) {
  __shared__ unsigned short k_lds[64][40];
  __shared__ unsigned short vt_lds[32][72];
  __shared__ unsigned short p_lds[4][16][72];
  int bh = blockIdx.y;
  int b = bh >> 3, hh = bh & 7;
  int q0 = blockIdx.x * 64;
  int t = threadIdx.x, lane = t & 63, w = t >> 6;
  int lm = lane & 15, lg = lane >> 4;

  // Q fragment, roped in-register
  int qrow = q0 + w*16 + lm;
  int qtk = qrow < 999 ? qrow : 999;
  int qtokg = b*1000 + qtk;
  s16x8 qf;
  {
    u16x8 raw = *(const u16x8*)&qh[(size_t)(bh*1000 + qtk)*HD_ + lg*8];
    f32x4 c4 = *(const f32x4*)&cosb[(size_t)qtokg*NP_ + lg*4];
    f32x4 s4 = *(const f32x4*)&sinb[(size_t)qtokg*NP_ + lg*4];
#pragma unroll
    for (int m = 0; m < 4; ++m) {
      float t1 = bf2f(raw[2*m]), t2 = bf2f(raw[2*m+1]);
      float e = t1*c4[m] - t2*s4[m];
      float o = t1*s4[m] + t2*c4[m];
      qf[2*m]   = (short)f2bf(e);
      qf[2*m+1] = (short)f2bf(o);
    }
  }

  float m_run[4], l_run[4];
  f32x4 o_acc[2];
#pragma unroll
  for (int i = 0; i < 4; ++i) { m_run[i] = -1e30f; l_run[i] = 0.f; }
  o_acc[0] = (f32x4){0.f,0.f,0.f,0.f};
  o_acc[1] = (f32x4){0.f,0.f,0.f,0.f};

  for (int ch = 0; ch < 16; ++ch) {
    int c0 = ch * 64;
    __syncthreads();
    // stage roped K
    for (int it = 0; it < 4; ++it) {
      int pi = it*256 + t;
      int key = pi >> 4, pp = pi & 15;
      int tk = c0 + key; tk = tk < 999 ? tk : 999;
      int tokg = b*1000 + tk;
      unsigned raw = *(const unsigned*)&kh[(size_t)(bh*1000 + tk)*HD_ + pp*2];
      float cc = cosb[(size_t)tokg*NP_ + pp], scn = sinb[(size_t)tokg*NP_ + pp];
      float t1 = bf2f((unsigned short)(raw & 0xFFFFu));
      float t2 = bf2f((unsigned short)(raw >> 16));
      float e = t1*cc - t2*scn, od = t1*scn + t2*cc;
      unsigned outp = (unsigned)f2bf(e) | ((unsigned)f2bf(od) << 16);
      *(unsigned*)&k_lds[key][pp*2] = outp;
    }
    // stage V transposed
    for (int it = 0; it < 4; ++it) {
      int e2 = it*256 + t;
      int key = e2 >> 4, dp = e2 & 15;
      int tk = c0 + key; tk = tk < 999 ? tk : 999;
      unsigned raw = *(const unsigned*)&vh[(size_t)(bh*1000 + tk)*HD_ + dp*2];
      vt_lds[dp*2][key]   = (unsigned short)(raw & 0xFFFFu);
      vt_lds[dp*2+1][key] = (unsigned short)(raw >> 16);
    }
    __syncthreads();
    // S = Q K^T
    f32x4 sacc[4];
#pragma unroll
    for (int nt = 0; nt < 4; ++nt) {
      sacc[nt] = (f32x4){0.f,0.f,0.f,0.f};
      s16x8 bb = *(const s16x8*)&k_lds[nt*16 + lm][lg*8];
      sacc[nt] = mfma_bf16(qf, bb, sacc[nt]);
    }
    const float scale = 0.17677669529663687f;
#pragma unroll
    for (int nt = 0; nt < 4; ++nt) {
      int col = c0 + nt*16 + lm;
      bool valid = col < 1000;
#pragma unroll
      for (int i = 0; i < 4; ++i) sacc[nt][i] = valid ? sacc[nt][i]*scale : -1e30f;
    }
#pragma unroll
    for (int i = 0; i < 4; ++i) {
      float mx = fmaxf(fmaxf(sacc[0][i], sacc[1][i]), fmaxf(sacc[2][i], sacc[3][i]));
      for (int m = 1; m < 16; m <<= 1) mx = fmaxf(mx, __shfl_xor(mx, m));
      float mn = fmaxf(m_run[i], mx);
      float alpha = __expf(m_run[i] - mn);
      float rsum = 0.f;
#pragma unroll
      for (int nt = 0; nt < 4; ++nt) { float p = __expf(sacc[nt][i] - mn); sacc[nt][i] = p; rsum += p; }
      for (int m = 1; m < 16; m <<= 1) rsum += __shfl_xor(rsum, m);
      l_run[i] = l_run[i]*alpha + rsum;
      m_run[i] = mn;
      o_acc[0][i] *= alpha; o_acc[1][i] *= alpha;
    }
    // P -> LDS (per-wave region; same-wave RAW, compiler orders)
#pragma unroll
    for (int nt = 0; nt < 4; ++nt)
#pragma unroll
      for (int i = 0; i < 4; ++i)
        p_lds[w][lg*4 + i][nt*16 + lm] = f2bf(sacc[nt][i]);
    // O += P V
#pragma unroll
    for (int kk = 0; kk < 2; ++kk) {
      s16x8 pf = *(const s16x8*)&p_lds[w][lm][kk*32 + lg*8];
#pragma unroll
      for (int dt = 0; dt < 2; ++dt) {
        s16x8 vf = *(const s16x8*)&vt_lds[dt*16 + lm][kk*32 + lg*8];
        o_acc[dt] = mfma_bf16(pf, vf, o_acc[dt]);
      }
    }
  }
#pragma unroll
  for (int i = 0; i < 4; ++i) {
    int qr = q0 + w*16 + lg*4 + i;
    if (qr < 1000) {
      float innorm = 1.0f / l_run[i];
      int tokg = b*1000 + qr;
#pragma unroll
      for (int dt = 0; dt < 2; ++dt)
        obuf[(size_t)tokg*D_ + hh*HD_ + dt*16 + lm] = f2bf(o_acc[dt][i] * innorm);
    }
  }
}

// ---------------- Wo GEMM + residual + scatter into d_out ----------------
__global__ __launch_bounds__(256) void wo_scatter(
    const unsigned short* obuf, const unsigned short* Wot,
    const float* queries, const int* idx, float* out) {
  __shared__ unsigned short a_lds[64][264];
  int m0 = blockIdx.x * 64;
  int t = threadIdx.x, lane = t & 63, w = t >> 6;
  int lm = lane & 15, lg = lane >> 4;
  for (int it = 0; it < 8; ++it) {
    int c = it*256 + t;
    int row = c >> 5, off = (c & 31) * 8;
    *(uint4*)&a_lds[row][off] = *(const uint4*)&obuf[(size_t)(m0+row)*D_ + off];
  }
  __syncthreads();
  f32x4 acc[16];
#pragma unroll
  for (int i = 0; i < 16; ++i) acc[i] = (f32x4){0.f,0.f,0.f,0.f};
#pragma unroll
  for (int ks = 0; ks < 8; ++ks) {
    s16x8 a = *(const s16x8*)&a_lds[w*16 + lm][ks*32 + lg*8];
#pragma unroll
    for (int nt = 0; nt < 16; ++nt) {
      s16x8 bb = *(const s16x8*)&Wot[(size_t)(nt*16 + lm)*D_ + ks*32 + lg*8];
      acc[nt] = mfma_bf16(a, bb, acc[nt]);
    }
  }
#pragma unroll
  for (int i = 0; i < 4; ++i) {
    int row = w*16 + lg*4 + i;
    int g = idx[m0 + row];
#pragma unroll
    for (int nt = 0; nt < 16; ++nt) {
      int col = nt*16 + lm;
      size_t ad = (size_t)g*D_ + col;
      out[ad] = queries[ad] + acc[nt][i];
    }
  }
}

// ---------------- fused LN2 + FFN (in-place on d_out), the dominant kernel ----------------
__global__ __launch_bounds__(256) void ffn_kernel(
    float* out, const unsigned short* W1t, const unsigned short* W2t,
    const float* b1, const float* b2, const float* g2, const float* bb2) {
  __shared__ unsigned short h2_lds[64][264];
  __shared__ unsigned short c1_lds[64][136];
  __shared__ float mu_s[64], rs_s[64];
  int m0 = blockIdx.x * 64;
  int t = threadIdx.x, lane = t & 63, w = t >> 6;
  int lm = lane & 15, lg = lane >> 4;
  // phase 1: LN stats (wave w owns rows w*16..w*16+15)
  for (int rr = 0; rr < 16; ++rr) {
    int row = w*16 + rr;
    f32x4 x = *(const f32x4*)&out[(size_t)(m0+row)*D_ + lane*4];
    float s1 = x[0]+x[1]+x[2]+x[3];
    float s2 = x[0]*x[0]+x[1]*x[1]+x[2]*x[2]+x[3]*x[3];
    for (int m = 1; m < 64; m <<= 1) { s1 += __shfl_xor(s1, m); s2 += __shfl_xor(s2, m); }
    if (lane == 0) {
      float mu = s1 / D_;
      mu_s[row] = mu;
      rs_s[row] = 1.0f / sqrtf(s2 / D_ - mu*mu + 1e-5f);
    }
  }
  __syncthreads();
  // phase 2: h2 = LN(x) bf16 into LDS
  for (int it = 0; it < 8; ++it) {
    int c = it*256 + t;
    int row = c >> 5, k8 = (c & 31) * 8;
    const float* p = &out[(size_t)(m0+row)*D_ + k8];
    float mu = mu_s[row], rs = rs_s[row];
    u16x8 hv;
#pragma unroll
    for (int j = 0; j < 8; ++j) hv[j] = f2bf((p[j] - mu) * rs * g2[k8+j] + bb2[k8+j]);
    *(u16x8*)&h2_lds[row][k8] = hv;
  }
  __syncthreads();
  f32x4 acc2[4][4];
#pragma unroll
  for (int mi = 0; mi < 4; ++mi)
#pragma unroll
    for (int nj = 0; nj < 4; ++nj) acc2[mi][nj] = (f32x4){0.f,0.f,0.f,0.f};

  for (int chn = 0; chn < 8; ++chn) {
    int d0 = chn * 128;
    f32x4 acc1[4][2];
#pragma unroll
    for (int mi = 0; mi < 4; ++mi) { acc1[mi][0] = (f32x4){0.f,0.f,0.f,0.f}; acc1[mi][1] = (f32x4){0.f,0.f,0.f,0.f}; }
#pragma unroll
    for (int ks = 0; ks < 8; ++ks) {
      s16x8 a[4];
#pragma unroll
      for (int mi = 0; mi < 4; ++mi) a[mi] = *(const s16x8*)&h2_lds[mi*16 + lm][ks*32 + lg*8];
#pragma unroll
      for (int ni = 0; ni < 2; ++ni) {
        s16x8 bb = *(const s16x8*)&W1t[(size_t)(d0 + w*32 + ni*16 + lm)*D_ + ks*32 + lg*8];
#pragma unroll
        for (int mi = 0; mi < 4; ++mi) acc1[mi][ni] = mfma_bf16(a[mi], bb, acc1[mi][ni]);
      }
    }
    // gelu(tanh approx) -> c1 bf16
#pragma unroll
    for (int ni = 0; ni < 2; ++ni) {
      int colc = w*32 + ni*16 + lm;
      float bias = b1[d0 + colc];
#pragma unroll
      for (int mi = 0; mi < 4; ++mi)
#pragma unroll
        for (int i = 0; i < 4; ++i) {
          float xv = acc1[mi][ni][i] + bias;
          float z = 0.7978845608028654f * (xv + 0.044715f * xv * xv * xv);
          float e = __expf(-2.0f * fabsf(z));
          float th = copysignf((1.0f - e) / (1.0f + e), z);
          c1_lds[mi*16 + lg*4 + i][colc] = f2bf(0.5f * xv * (1.0f + th));
        }
    }
    __syncthreads();
    // GEMM2 partial accumulate
#pragma unroll
    for (int ks = 0; ks < 4; ++ks) {
      s16x8 a[4];
#pragma unroll
      for (int mi = 0; mi < 4; ++mi) a[mi] = *(const s16x8*)&c1_lds[mi*16 + lm][ks*32 + lg*8];
#pragma unroll
      for (int nj = 0; nj < 4; ++nj) {
        s16x8 bb = *(const s16x8*)&W2t[(size_t)(w*64 + nj*16 + lm)*DFF_ + d0 + ks*32 + lg*8];
#pragma unroll
        for (int mi = 0; mi < 4; ++mi) acc2[mi][nj] = mfma_bf16(a[mi], bb, acc2[mi][nj]);
      }
    }
    __syncthreads();
  }
#pragma unroll
  for (int nj = 0; nj < 4; ++nj) {
    int col = w*64 + nj*16 + lm;
    float bias = b2[col];
#pragma unroll
    for (int mi = 0; mi < 4; ++mi)
#pragma unroll
      for (int i = 0; i < 4; ++i) {
        int row = mi*16 + lg*4 + i;
        size_t ad = (size_t)(m0+row)*D_ + col;
        out[ad] = out[ad] + acc2[mi][nj][i] + bias;
      }
  }
}

extern "C" void kernel_launch(void* const* d_in, const int* in_sizes, int n_in,
                              void* d_out, int out_size, void* d_ws, size_t ws_size,
                              hipStream_t stream) {
  const float* queries = (const float*)d_in[0];
  const float* sal   = (const float*)d_in[2];
  const float* ele   = (const float*)d_in[3];
  const int*   spat  = (const int*)d_in[4];
  const int*   shapes= (const int*)d_in[6];
  const float* Wqkv  = (const float*)d_in[7];
  const float* Wo    = (const float*)d_in[8];
  const float* ln1g  = (const float*)d_in[9];
  const float* ln1b  = (const float*)d_in[10];
  const float* W1    = (const float*)d_in[11];
  const float* b1    = (const float*)d_in[12];
  const float* W2    = (const float*)d_in[13];
  const float* b2    = (const float*)d_in[14];
  const float* ln2g  = (const float*)d_in[15];
  const float* ln2b  = (const float*)d_in[16];
  float* out = (float*)d_out;

  char* ws = (char*)d_ws;
  size_t off = 0;
  auto alloc = [&](size_t bytes) -> void* {
    void* p = ws + off;
    off = (off + bytes + 255) & ~(size_t)255;
    return p;
  };
  int*            idxb  = (int*)alloc((size_t)NTOK * 4);
  unsigned short* h     = (unsigned short*)alloc((size_t)NTOK * D_ * 2);
  float*          cosb  = (float*)alloc((size_t)NTOK * NP_ * 4);
  float*          sinb  = (float*)alloc((size_t)NTOK * NP_ * 4);
  unsigned short* qh    = (unsigned short*)alloc((size_t)NTOK * D_ * 2);
  unsigned short* kh    = (unsigned short*)alloc((size_t)NTOK * D_ * 2);
  unsigned short* vh    = (unsigned short*)alloc((size_t)NTOK * D_ * 2);
  unsigned short* obuf  = (unsigned short*)alloc((size_t)NTOK * D_ * 2);
  unsigned short* Wqkvt = (unsigned short*)alloc((size_t)768 * 256 * 2);
  unsigned short* Wot   = (unsigned short*)alloc((size_t)256 * 256 * 2);
  unsigned short* W1t   = (unsigned short*)alloc((size_t)1024 * 256 * 2);
  unsigned short* W2t   = (unsigned short*)alloc((size_t)256 * 1024 * 2);

  hipMemcpyAsync(out, queries, (size_t)NALL * D_ * 4, hipMemcpyDeviceToDevice, stream);
  prep_weights<<<512, 256, 0, stream>>>(Wqkv, Wo, W1, W2, Wqkvt, Wot, W1t, W2t);
  topk_kernel<<<B_, 1024, 0, stream>>>(ele, sal, idxb);
  gather_ln_rope<<<NTOK, 256, 0, stream>>>(queries, idxb, spat, shapes, ln1g, ln1b, h, cosb, sinb);
  qkv_gemm<<<dim3(6, 125), 256, 0, stream>>>(h, Wqkvt, qh, kh, vh);
  attn_kernel<<<dim3(16, 64), 256, 0, stream>>>(qh, kh, vh, cosb, sinb, obuf);
  wo_scatter<<<125, 256, 0, stream>>>(obuf, Wot, queries, idxb, out);
  ffn_kernel<<<2048, 256, 0, stream>>>(out, W1t, W2t, b1, b2, ln2g, ln2b);
}

// Round 2
// 649.064 us; speedup vs baseline: 2.1874x; 2.1874x over previous
//
#include <hip/hip_runtime.h>
#include <hip/hip_bf16.h>
#include <math.h>

#define B_   8
#define L_   16384
#define D_   256
#define H_   8
#define DFF_ 1024
#define KSEL 1000
#define NTOK (B_*KSEL)   // 8000
#define NALL (B_*L_)     // 131072
#define HD_  32
#define NP_  16

typedef float f32x4 __attribute__((ext_vector_type(4)));
typedef short s16x8 __attribute__((ext_vector_type(8)));
typedef unsigned short u16x8 __attribute__((ext_vector_type(8)));

static __device__ __forceinline__ unsigned short f2bf(float f) {
  unsigned u = __float_as_uint(f);
  u += 0x7FFFu + ((u >> 16) & 1u);       // RNE
  return (unsigned short)(u >> 16);
}
static __device__ __forceinline__ float bf2f(unsigned short h) {
  return __uint_as_float(((unsigned)h) << 16);
}
static __device__ __forceinline__ f32x4 mfma_bf16(s16x8 a, s16x8 b, f32x4 c) {
  return __builtin_amdgcn_mfma_f32_16x16x32_bf16(a, b, c, 0, 0, 0);
}

// ---------------- weight prep: f32 [K][N] -> bf16 [N][K], tiled transpose ----------------
__global__ __launch_bounds__(256) void transpose_w(const float* src, unsigned short* dst,
                                                   int K, int N) {
  __shared__ float tile[32][33];
  int k0 = blockIdx.y * 32;
  int n0 = blockIdx.x * 32;
  int tx = threadIdx.x & 31, ty = threadIdx.x >> 5;   // 32 x 8
#pragma unroll
  for (int r = 0; r < 32; r += 8)
    tile[ty + r][tx] = src[(size_t)(k0 + ty + r) * N + n0 + tx];
  __syncthreads();
#pragma unroll
  for (int r = 0; r < 32; r += 8)
    dst[(size_t)(n0 + ty + r) * K + k0 + tx] = f2bf(tile[tx][ty + r]);
}

// ---------------- per-batch top-K (deterministic, registers + ballot compaction) ----------------
__global__ __launch_bounds__(1024) void topk_kernel(const float* es, const float* ss, int* out_idx) {
  __shared__ int wsum[16];
  __shared__ int chunk_base;
  int b = blockIdx.x;
  int t = threadIdx.x;
  int lane = t & 63, w = t >> 6;
  int base = b * L_;
  unsigned kreg[16];
#pragma unroll
  for (int ci = 0; ci < 16; ++ci) {
    int i = ci * 1024 + t;
    float f = es[base + i] + ss[base + i];
    unsigned u = __float_as_uint(f);
    kreg[ci] = (u & 0x80000000u) ? ~u : (u | 0x80000000u);   // sortable
  }
  // bitwise search: max v with count(>= v) >= K  ->  v = K-th largest key
  unsigned v = 0;
  for (int bit = 31; bit >= 0; --bit) {
    unsigned cand = v | (1u << bit);
    int c = 0;
#pragma unroll
    for (int ci = 0; ci < 16; ++ci) c += (kreg[ci] >= cand) ? 1 : 0;
    for (int m = 1; m < 64; m <<= 1) c += __shfl_xor(c, m);
    if (lane == 0) wsum[w] = c;
    __syncthreads();
    int tot = 0;
#pragma unroll
    for (int j = 0; j < 16; ++j) tot += wsum[j];
    if (tot >= KSEL) v = cand;
    __syncthreads();
  }
  // pass 0: compact indices with key > v (count C < K);
  // pass 1: fill remaining K-C slots with key == v (count(==v) >= K-C), pos<K guard.
  if (t == 0) chunk_base = 0;
  __syncthreads();
  for (int pass = 0; pass < 2; ++pass) {
    for (int ci = 0; ci < 16; ++ci) {
      bool pred = (pass == 0) ? (kreg[ci] > v) : (kreg[ci] == v);
      unsigned long long mask = __ballot(pred);
      if (lane == 0) wsum[w] = __popcll(mask);
      __syncthreads();
      int wbase = chunk_base;
      for (int j = 0; j < w; ++j) wbase += wsum[j];
      if (pred) {
        int pos = wbase + __popcll(mask & ((1ull << lane) - 1ull));
        if (pos < KSEL) out_idx[b * KSEL + pos] = base + ci * 1024 + t;
      }
      __syncthreads();
      if (t == 0) { int tt = 0; for (int j = 0; j < 16; ++j) tt += wsum[j]; chunk_base += tt; }
      __syncthreads();
    }
  }
}

// ---------------- gather + LN1 + rope cos/sin tables ----------------
__global__ __launch_bounds__(256) void gather_ln_rope(
    const float* queries, const int* idx, const int* spat, const int* shapes,
    const float* g1, const float* b1ln, unsigned short* h, float* cosb, float* sinb) {
  int tok = blockIdx.x;
  int t = threadIdx.x;
  int gidx = idx[tok];
  float x = queries[(size_t)gidx * D_ + t];
  float s1 = x, s2 = x * x;
  for (int m = 1; m < 64; m <<= 1) { s1 += __shfl_xor(s1, m); s2 += __shfl_xor(s2, m); }
  __shared__ float p1[4], p2[4];
  int w = t >> 6;
  if ((t & 63) == 0) { p1[w] = s1; p2[w] = s2; }
  __syncthreads();
  float tot  = p1[0] + p1[1] + p1[2] + p1[3];
  float tot2 = p2[0] + p2[1] + p2[2] + p2[3];
  float mu = tot / D_;
  float var = tot2 / D_ - mu * mu;
  float rs = 1.0f / sqrtf(var + 1e-5f);
  h[(size_t)tok * D_ + t] = f2bf((x - mu) * rs * g1[t] + b1ln[t]);
  if (t < NP_) {
    int yy = spat[1*(size_t)NALL + gidx];
    int xx = spat[2*(size_t)NALL + gidx];
    int lv = spat[3*(size_t)NALL + gidx];
    float ang;
    if (t < 6) {
      float sc = (float)shapes[0] / (float)shapes[lv*2+0];
      ang = (float)yy * sc * powf(100.0f, -(float)t / 6.0f);
    } else if (t < 12) {
      float sc = (float)shapes[1] / (float)shapes[lv*2+1];
      ang = (float)xx * sc * powf(100.0f, -(float)(t-6) / 6.0f);
    } else {
      ang = (float)lv * powf(10.0f, -(float)(t-12) / 4.0f);
    }
    cosb[tok*NP_ + t] = cosf(ang);
    sinb[tok*NP_ + t] = sinf(ang);
  }
}

// ---------------- qkv GEMM: (8000x256) @ Wqkv -> q/k/v head-arranged bf16 ----------------
__global__ __launch_bounds__(256) void qkv_gemm(
    const unsigned short* h, const unsigned short* Wt,
    unsigned short* qh, unsigned short* kh, unsigned short* vh) {
  __shared__ unsigned short a_lds[64][264];
  int m0 = blockIdx.y * 64;
  int n0 = blockIdx.x * 128;
  int t = threadIdx.x, lane = t & 63, w = t >> 6;
  int lm = lane & 15, lg = lane >> 4;
  for (int it = 0; it < 8; ++it) {
    int c = it*256 + t;
    int row = c >> 5, off = (c & 31) * 8;
    *(uint4*)&a_lds[row][off] = *(const uint4*)&h[(size_t)(m0+row)*D_ + off];
  }
  __syncthreads();
  f32x4 acc[8];
#pragma unroll
  for (int i = 0; i < 8; ++i) acc[i] = (f32x4){0.f,0.f,0.f,0.f};
#pragma unroll
  for (int ks = 0; ks < 8; ++ks) {
    s16x8 a = *(const s16x8*)&a_lds[w*16 + lm][ks*32 + lg*8];
#pragma unroll
    for (int nt = 0; nt < 8; ++nt) {
      s16x8 bb = *(const s16x8*)&Wt[(size_t)(n0 + nt*16 + lm)*D_ + ks*32 + lg*8];
      acc[nt] = mfma_bf16(a, bb, acc[nt]);
    }
  }
#pragma unroll
  for (int i = 0; i < 4; ++i) {
    int row = w*16 + lg*4 + i;
    int tok = m0 + row;
    int b = tok / 1000, tk = tok - b*1000;
#pragma unroll
    for (int nt = 0; nt < 8; ++nt) {
      int col = n0 + nt*16 + lm;
      int part = col >> 8;
      int within = col & 255;
      int head = within >> 5, d = within & 31;
      unsigned short* dst = part == 0 ? qh : (part == 1 ? kh : vh);
      dst[(size_t)((b*H_ + head)*1000 + tk)*HD_ + d] = f2bf(acc[nt][i]);
    }
  }
}

// ---------------- flash attention per (b,h), rope applied at operand load ----------------
__global__ __launch_bounds__(256) void attn_kernel(
    const unsigned short* qh, const unsigned short* kh, const unsigned short* vh,
    const float* cosb, const float* sinb, unsigned short* obuf) {
  __shared__ unsigned short k_lds[64][40];
  __shared__ unsigned short vt_lds[32][72];
  __shared__ unsigned short p_lds[4][16][72];
  int bh = blockIdx.y;
  int b = bh >> 3, hh = bh & 7;
  int q0 = blockIdx.x * 64;
  int t = threadIdx.x, lane = t & 63, w = t >> 6;
  int lm = lane & 15, lg = lane >> 4;

  // Q fragment, roped in-register
  int qrow = q0 + w*16 + lm;
  int qtk = qrow < 999 ? qrow : 999;
  int qtokg = b*1000 + qtk;
  s16x8 qf;
  {
    u16x8 raw = *(const u16x8*)&qh[(size_t)(bh*1000 + qtk)*HD_ + lg*8];
    f32x4 c4 = *(const f32x4*)&cosb[(size_t)qtokg*NP_ + lg*4];
    f32x4 s4 = *(const f32x4*)&sinb[(size_t)qtokg*NP_ + lg*4];
#pragma unroll
    for (int m = 0; m < 4; ++m) {
      float t1 = bf2f(raw[2*m]), t2 = bf2f(raw[2*m+1]);
      float e = t1*c4[m] - t2*s4[m];
      float o = t1*s4[m] + t2*c4[m];
      qf[2*m]   = (short)f2bf(e);
      qf[2*m+1] = (short)f2bf(o);
    }
  }

  float m_run[4], l_run[4];
  f32x4 o_acc[2];
#pragma unroll
  for (int i = 0; i < 4; ++i) { m_run[i] = -1e30f; l_run[i] = 0.f; }
  o_acc[0] = (f32x4){0.f,0.f,0.f,0.f};
  o_acc[1] = (f32x4){0.f,0.f,0.f,0.f};

  for (int ch = 0; ch < 16; ++ch) {
    int c0 = ch * 64;
    __syncthreads();
    // stage roped K
    for (int it = 0; it < 4; ++it) {
      int pi = it*256 + t;
      int key = pi >> 4, pp = pi & 15;
      int tk = c0 + key; tk = tk < 999 ? tk : 999;
      int tokg = b*1000 + tk;
      unsigned raw = *(const unsigned*)&kh[(size_t)(bh*1000 + tk)*HD_ + pp*2];
      float cc = cosb[(size_t)tokg*NP_ + pp], scn = sinb[(size_t)tokg*NP_ + pp];
      float t1 = bf2f((unsigned short)(raw & 0xFFFFu));
      float t2 = bf2f((unsigned short)(raw >> 16));
      float e = t1*cc - t2*scn, od = t1*scn + t2*cc;
      unsigned outp = (unsigned)f2bf(e) | ((unsigned)f2bf(od) << 16);
      *(unsigned*)&k_lds[key][pp*2] = outp;
    }
    // stage V transposed
    for (int it = 0; it < 4; ++it) {
      int e2 = it*256 + t;
      int key = e2 >> 4, dp = e2 & 15;
      int tk = c0 + key; tk = tk < 999 ? tk : 999;
      unsigned raw = *(const unsigned*)&vh[(size_t)(bh*1000 + tk)*HD_ + dp*2];
      vt_lds[dp*2][key]   = (unsigned short)(raw & 0xFFFFu);
      vt_lds[dp*2+1][key] = (unsigned short)(raw >> 16);
    }
    __syncthreads();
    // S = Q K^T
    f32x4 sacc[4];
#pragma unroll
    for (int nt = 0; nt < 4; ++nt) {
      sacc[nt] = (f32x4){0.f,0.f,0.f,0.f};
      s16x8 bb = *(const s16x8*)&k_lds[nt*16 + lm][lg*8];
      sacc[nt] = mfma_bf16(qf, bb, sacc[nt]);
    }
    const float scale = 0.17677669529663687f;
#pragma unroll
    for (int nt = 0; nt < 4; ++nt) {
      int col = c0 + nt*16 + lm;
      bool valid = col < 1000;
#pragma unroll
      for (int i = 0; i < 4; ++i) sacc[nt][i] = valid ? sacc[nt][i]*scale : -1e30f;
    }
#pragma unroll
    for (int i = 0; i < 4; ++i) {
      float mx = fmaxf(fmaxf(sacc[0][i], sacc[1][i]), fmaxf(sacc[2][i], sacc[3][i]));
      for (int m = 1; m < 16; m <<= 1) mx = fmaxf(mx, __shfl_xor(mx, m));
      float mn = fmaxf(m_run[i], mx);
      float alpha = __expf(m_run[i] - mn);
      float rsum = 0.f;
#pragma unroll
      for (int nt = 0; nt < 4; ++nt) { float p = __expf(sacc[nt][i] - mn); sacc[nt][i] = p; rsum += p; }
      for (int m = 1; m < 16; m <<= 1) rsum += __shfl_xor(rsum, m);
      l_run[i] = l_run[i]*alpha + rsum;
      m_run[i] = mn;
      o_acc[0][i] *= alpha; o_acc[1][i] *= alpha;
    }
    // P -> LDS (per-wave region; same-wave RAW, compiler orders)
#pragma unroll
    for (int nt = 0; nt < 4; ++nt)
#pragma unroll
      for (int i = 0; i < 4; ++i)
        p_lds[w][lg*4 + i][nt*16 + lm] = f2bf(sacc[nt][i]);
    // O += P V
#pragma unroll
    for (int kk = 0; kk < 2; ++kk) {
      s16x8 pf = *(const s16x8*)&p_lds[w][lm][kk*32 + lg*8];
#pragma unroll
      for (int dt = 0; dt < 2; ++dt) {
        s16x8 vf = *(const s16x8*)&vt_lds[dt*16 + lm][kk*32 + lg*8];
        o_acc[dt] = mfma_bf16(pf, vf, o_acc[dt]);
      }
    }
  }
#pragma unroll
  for (int i = 0; i < 4; ++i) {
    int qr = q0 + w*16 + lg*4 + i;
    if (qr < 1000) {
      float innorm = 1.0f / l_run[i];
      int tokg = b*1000 + qr;
#pragma unroll
      for (int dt = 0; dt < 2; ++dt)
        obuf[(size_t)tokg*D_ + hh*HD_ + dt*16 + lm] = f2bf(o_acc[dt][i] * innorm);
    }
  }
}

// ---------------- Wo GEMM + residual + scatter into d_out ----------------
__global__ __launch_bounds__(256) void wo_scatter(
    const unsigned short* obuf, const unsigned short* Wot,
    const float* queries, const int* idx, float* out) {
  __shared__ unsigned short a_lds[64][264];
  int m0 = blockIdx.x * 64;
  int t = threadIdx.x, lane = t & 63, w = t >> 6;
  int lm = lane & 15, lg = lane >> 4;
  for (int it = 0; it < 8; ++it) {
    int c = it*256 + t;
    int row = c >> 5, off = (c & 31) * 8;
    *(uint4*)&a_lds[row][off] = *(const uint4*)&obuf[(size_t)(m0+row)*D_ + off];
  }
  __syncthreads();
  f32x4 acc[16];
#pragma unroll
  for (int i = 0; i < 16; ++i) acc[i] = (f32x4){0.f,0.f,0.f,0.f};
#pragma unroll
  for (int ks = 0; ks < 8; ++ks) {
    s16x8 a = *(const s16x8*)&a_lds[w*16 + lm][ks*32 + lg*8];
#pragma unroll
    for (int nt = 0; nt < 16; ++nt) {
      s16x8 bb = *(const s16x8*)&Wot[(size_t)(nt*16 + lm)*D_ + ks*32 + lg*8];
      acc[nt] = mfma_bf16(a, bb, acc[nt]);
    }
  }
#pragma unroll
  for (int i = 0; i < 4; ++i) {
    int row = w*16 + lg*4 + i;
    int g = idx[m0 + row];
#pragma unroll
    for (int nt = 0; nt < 16; ++nt) {
      int col = nt*16 + lm;
      size_t ad = (size_t)g*D_ + col;
      out[ad] = queries[ad] + acc[nt][i];
    }
  }
}

// ---------------- fused LN2 + FFN (in-place on d_out), the dominant kernel ----------------
__global__ __launch_bounds__(256) void ffn_kernel(
    float* out, const unsigned short* W1t, const unsigned short* W2t,
    const float* b1, const float* b2, const float* g2, const float* bb2) {
  __shared__ unsigned short h2_lds[64][264];
  __shared__ unsigned short c1_lds[64][136];
  __shared__ float mu_s[64], rs_s[64];
  int m0 = blockIdx.x * 64;
  int t = threadIdx.x, lane = t & 63, w = t >> 6;
  int lm = lane & 15, lg = lane >> 4;
  // phase 1: LN stats (wave w owns rows w*16..w*16+15)
  for (int rr = 0; rr < 16; ++rr) {
    int row = w*16 + rr;
    f32x4 x = *(const f32x4*)&out[(size_t)(m0+row)*D_ + lane*4];
    float s1 = x[0]+x[1]+x[2]+x[3];
    float s2 = x[0]*x[0]+x[1]*x[1]+x[2]*x[2]+x[3]*x[3];
    for (int m = 1; m < 64; m <<= 1) { s1 += __shfl_xor(s1, m); s2 += __shfl_xor(s2, m); }
    if (lane == 0) {
      float mu = s1 / D_;
      mu_s[row] = mu;
      rs_s[row] = 1.0f / sqrtf(s2 / D_ - mu*mu + 1e-5f);
    }
  }
  __syncthreads();
  // phase 2: h2 = LN(x) bf16 into LDS
  for (int it = 0; it < 8; ++it) {
    int c = it*256 + t;
    int row = c >> 5, k8 = (c & 31) * 8;
    const float* p = &out[(size_t)(m0+row)*D_ + k8];
    float mu = mu_s[row], rs = rs_s[row];
    u16x8 hv;
#pragma unroll
    for (int j = 0; j < 8; ++j) hv[j] = f2bf((p[j] - mu) * rs * g2[k8+j] + bb2[k8+j]);
    *(u16x8*)&h2_lds[row][k8] = hv;
  }
  __syncthreads();
  f32x4 acc2[4][4];
#pragma unroll
  for (int mi = 0; mi < 4; ++mi)
#pragma unroll
    for (int nj = 0; nj < 4; ++nj) acc2[mi][nj] = (f32x4){0.f,0.f,0.f,0.f};

  for (int chn = 0; chn < 8; ++chn) {
    int d0 = chn * 128;
    f32x4 acc1[4][2];
#pragma unroll
    for (int mi = 0; mi < 4; ++mi) { acc1[mi][0] = (f32x4){0.f,0.f,0.f,0.f}; acc1[mi][1] = (f32x4){0.f,0.f,0.f,0.f}; }
#pragma unroll
    for (int ks = 0; ks < 8; ++ks) {
      s16x8 a[4];
#pragma unroll
      for (int mi = 0; mi < 4; ++mi) a[mi] = *(const s16x8*)&h2_lds[mi*16 + lm][ks*32 + lg*8];
#pragma unroll
      for (int ni = 0; ni < 2; ++ni) {
        s16x8 bb = *(const s16x8*)&W1t[(size_t)(d0 + w*32 + ni*16 + lm)*D_ + ks*32 + lg*8];
#pragma unroll
        for (int mi = 0; mi < 4; ++mi) acc1[mi][ni] = mfma_bf16(a[mi], bb, acc1[mi][ni]);
      }
    }
    // gelu(tanh approx) -> c1 bf16
#pragma unroll
    for (int ni = 0; ni < 2; ++ni) {
      int colc = w*32 + ni*16 + lm;
      float bias = b1[d0 + colc];
#pragma unroll
      for (int mi = 0; mi < 4; ++mi)
#pragma unroll
        for (int i = 0; i < 4; ++i) {
          float xv = acc1[mi][ni][i] + bias;
          float z = 0.7978845608028654f * (xv + 0.044715f * xv * xv * xv);
          float e = __expf(-2.0f * fabsf(z));
          float th = copysignf((1.0f - e) / (1.0f + e), z);
          c1_lds[mi*16 + lg*4 + i][colc] = f2bf(0.5f * xv * (1.0f + th));
        }
    }
    __syncthreads();
    // GEMM2 partial accumulate
#pragma unroll
    for (int ks = 0; ks < 4; ++ks) {
      s16x8 a[4];
#pragma unroll
      for (int mi = 0; mi < 4; ++mi) a[mi] = *(const s16x8*)&c1_lds[mi*16 + lm][ks*32 + lg*8];
#pragma unroll
      for (int nj = 0; nj < 4; ++nj) {
        s16x8 bb = *(const s16x8*)&W2t[(size_t)(w*64 + nj*16 + lm)*DFF_ + d0 + ks*32 + lg*8];
#pragma unroll
        for (int mi = 0; mi < 4; ++mi) acc2[mi][nj] = mfma_bf16(a[mi], bb, acc2[mi][nj]);
      }
    }
    __syncthreads();
  }
#pragma unroll
  for (int nj = 0; nj < 4; ++nj) {
    int col = w*64 + nj*16 + lm;
    float bias = b2[col];
#pragma unroll
    for (int mi = 0; mi < 4; ++mi)
#pragma unroll
      for (int i = 0; i < 4; ++i) {
        int row = mi*16 + lg*4 + i;
        size_t ad = (size_t)(m0+row)*D_ + col;
        out[ad] = out[ad] + acc2[mi][nj][i] + bias;
      }
  }
}

extern "C" void kernel_launch(void* const* d_in, const int* in_sizes, int n_in,
                              void* d_out, int out_size, void* d_ws, size_t ws_size,
                              hipStream_t stream) {
  const float* queries = (const float*)d_in[0];
  const float* sal   = (const float*)d_in[2];
  const float* ele   = (const float*)d_in[3];
  const int*   spat  = (const int*)d_in[4];
  const int*   shapes= (const int*)d_in[6];
  const float* Wqkv  = (const float*)d_in[7];
  const float* Wo    = (const float*)d_in[8];
  const float* ln1g  = (const float*)d_in[9];
  const float* ln1b  = (const float*)d_in[10];
  const float* W1    = (const float*)d_in[11];
  const float* b1    = (const float*)d_in[12];
  const float* W2    = (const float*)d_in[13];
  const float* b2    = (const float*)d_in[14];
  const float* ln2g  = (const float*)d_in[15];
  const float* ln2b  = (const float*)d_in[16];
  float* out = (float*)d_out;

  char* ws = (char*)d_ws;
  size_t off = 0;
  auto alloc = [&](size_t bytes) -> void* {
    void* p = ws + off;
    off = (off + bytes + 255) & ~(size_t)255;
    return p;
  };
  int*            idxb  = (int*)alloc((size_t)NTOK * 4);
  unsigned short* h     = (unsigned short*)alloc((size_t)NTOK * D_ * 2);
  float*          cosb  = (float*)alloc((size_t)NTOK * NP_ * 4);
  float*          sinb  = (float*)alloc((size_t)NTOK * NP_ * 4);
  unsigned short* qh    = (unsigned short*)alloc((size_t)NTOK * D_ * 2);
  unsigned short* kh    = (unsigned short*)alloc((size_t)NTOK * D_ * 2);
  unsigned short* vh    = (unsigned short*)alloc((size_t)NTOK * D_ * 2);
  unsigned short* obuf  = (unsigned short*)alloc((size_t)NTOK * D_ * 2);
  unsigned short* Wqkvt = (unsigned short*)alloc((size_t)768 * 256 * 2);
  unsigned short* Wot   = (unsigned short*)alloc((size_t)256 * 256 * 2);
  unsigned short* W1t   = (unsigned short*)alloc((size_t)1024 * 256 * 2);
  unsigned short* W2t   = (unsigned short*)alloc((size_t)256 * 1024 * 2);

  hipMemcpyAsync(out, queries, (size_t)NALL * D_ * 4, hipMemcpyDeviceToDevice, stream);
  // weights: src [K][N] -> dst [N][K]
  transpose_w<<<dim3(768/32, 256/32), 256, 0, stream>>>(Wqkv, Wqkvt, 256, 768);
  transpose_w<<<dim3(256/32, 256/32), 256, 0, stream>>>(Wo,   Wot,   256, 256);
  transpose_w<<<dim3(1024/32, 256/32), 256, 0, stream>>>(W1,  W1t,   256, 1024);
  transpose_w<<<dim3(256/32, 1024/32), 256, 0, stream>>>(W2,  W2t,  1024, 256);
  topk_kernel<<<B_, 1024, 0, stream>>>(ele, sal, idxb);
  gather_ln_rope<<<NTOK, 256, 0, stream>>>(queries, idxb, spat, shapes, ln1g, ln1b, h, cosb, sinb);
  qkv_gemm<<<dim3(6, 125), 256, 0, stream>>>(h, Wqkvt, qh, kh, vh);
  attn_kernel<<<dim3(16, 64), 256, 0, stream>>>(qh, kh, vh, cosb, sinb, obuf);
  wo_scatter<<<125, 256, 0, stream>>>(obuf, Wot, queries, idxb, out);
  ffn_kernel<<<2048, 256, 0, stream>>>(out, W1t, W2t, b1, b2, ln2g, ln2b);
}

// Round 3
// 507.818 us; speedup vs baseline: 2.7958x; 1.2781x over previous
//
#include <hip/hip_runtime.h>
#include <hip/hip_bf16.h>
#include <math.h>

#define B_   8
#define L_   16384
#define D_   256
#define H_   8
#define DFF_ 1024
#define KSEL 1000
#define NTOK (B_*KSEL)   // 8000
#define NALL (B_*L_)     // 131072
#define HD_  32
#define NP_  16

typedef float f32x4 __attribute__((ext_vector_type(4)));
typedef short s16x8 __attribute__((ext_vector_type(8)));
typedef unsigned short u16x8 __attribute__((ext_vector_type(8)));
typedef unsigned short u16x4 __attribute__((ext_vector_type(4)));

// hardware bf16 convert (fptrunc -> v_cvt_pk_bf16_f32 on gfx950), RNE
static __device__ __forceinline__ unsigned short f2bf(float f) {
  __bf16 b = (__bf16)f;
  return __builtin_bit_cast(unsigned short, b);
}
static __device__ __forceinline__ float bf2f(unsigned short h) {
  return __uint_as_float(((unsigned)h) << 16);
}
static __device__ __forceinline__ f32x4 mfma_bf16(s16x8 a, s16x8 b, f32x4 c) {
  return __builtin_amdgcn_mfma_f32_16x16x32_bf16(a, b, c, 0, 0, 0);
}

// ---------------- weight prep: f32 [K][N] -> bf16 [N][K], tiled transpose ----------------
__global__ __launch_bounds__(256) void transpose_w(const float* src, unsigned short* dst,
                                                   int K, int N) {
  __shared__ float tile[32][33];
  int k0 = blockIdx.y * 32;
  int n0 = blockIdx.x * 32;
  int tx = threadIdx.x & 31, ty = threadIdx.x >> 5;   // 32 x 8
#pragma unroll
  for (int r = 0; r < 32; r += 8)
    tile[ty + r][tx] = src[(size_t)(k0 + ty + r) * N + n0 + tx];
  __syncthreads();
#pragma unroll
  for (int r = 0; r < 32; r += 8)
    dst[(size_t)(n0 + ty + r) * K + k0 + tx] = f2bf(tile[tx][ty + r]);
}

// ---------------- per-batch top-K (deterministic, registers + ballot compaction) ----------------
__global__ __launch_bounds__(1024) void topk_kernel(const float* es, const float* ss, int* out_idx) {
  __shared__ int wsum[16];
  __shared__ int chunk_base;
  int b = blockIdx.x;
  int t = threadIdx.x;
  int lane = t & 63, w = t >> 6;
  int base = b * L_;
  unsigned kreg[16];
#pragma unroll
  for (int ci = 0; ci < 16; ++ci) {
    int i = ci * 1024 + t;
    float f = es[base + i] + ss[base + i];
    unsigned u = __float_as_uint(f);
    kreg[ci] = (u & 0x80000000u) ? ~u : (u | 0x80000000u);   // sortable
  }
  // bitwise search: max v with count(>= v) >= K  ->  v = K-th largest key
  unsigned v = 0;
  for (int bit = 31; bit >= 0; --bit) {
    unsigned cand = v | (1u << bit);
    int c = 0;
#pragma unroll
    for (int ci = 0; ci < 16; ++ci) c += (kreg[ci] >= cand) ? 1 : 0;
    for (int m = 1; m < 64; m <<= 1) c += __shfl_xor(c, m);
    if (lane == 0) wsum[w] = c;
    __syncthreads();
    int tot = 0;
#pragma unroll
    for (int j = 0; j < 16; ++j) tot += wsum[j];
    if (tot >= KSEL) v = cand;
    __syncthreads();
  }
  // pass 0: compact indices with key > v; pass 1: fill remainder with key == v (pos<K guard)
  if (t == 0) chunk_base = 0;
  __syncthreads();
  for (int pass = 0; pass < 2; ++pass) {
    for (int ci = 0; ci < 16; ++ci) {
      bool pred = (pass == 0) ? (kreg[ci] > v) : (kreg[ci] == v);
      unsigned long long mask = __ballot(pred);
      if (lane == 0) wsum[w] = __popcll(mask);
      __syncthreads();
      int wbase = chunk_base;
      for (int j = 0; j < w; ++j) wbase += wsum[j];
      if (pred) {
        int pos = wbase + __popcll(mask & ((1ull << lane) - 1ull));
        if (pos < KSEL) out_idx[b * KSEL + pos] = base + ci * 1024 + t;
      }
      __syncthreads();
      if (t == 0) { int tt = 0; for (int j = 0; j < 16; ++j) tt += wsum[j]; chunk_base += tt; }
      __syncthreads();
    }
  }
}

// ---------------- gather + LN1 + rope cos/sin tables ----------------
__global__ __launch_bounds__(256) void gather_ln_rope(
    const float* queries, const int* idx, const int* spat, const int* shapes,
    const float* g1, const float* b1ln, unsigned short* h, float* cosb, float* sinb) {
  int tok = blockIdx.x;
  int t = threadIdx.x;
  int gidx = idx[tok];
  float x = queries[(size_t)gidx * D_ + t];
  float s1 = x, s2 = x * x;
  for (int m = 1; m < 64; m <<= 1) { s1 += __shfl_xor(s1, m); s2 += __shfl_xor(s2, m); }
  __shared__ float p1[4], p2[4];
  int w = t >> 6;
  if ((t & 63) == 0) { p1[w] = s1; p2[w] = s2; }
  __syncthreads();
  float tot  = p1[0] + p1[1] + p1[2] + p1[3];
  float tot2 = p2[0] + p2[1] + p2[2] + p2[3];
  float mu = tot / D_;
  float var = tot2 / D_ - mu * mu;
  float rs = 1.0f / sqrtf(var + 1e-5f);
  h[(size_t)tok * D_ + t] = f2bf((x - mu) * rs * g1[t] + b1ln[t]);
  if (t < NP_) {
    int yy = spat[1*(size_t)NALL + gidx];
    int xx = spat[2*(size_t)NALL + gidx];
    int lv = spat[3*(size_t)NALL + gidx];
    float ang;
    if (t < 6) {
      float sc = (float)shapes[0] / (float)shapes[lv*2+0];
      ang = (float)yy * sc * powf(100.0f, -(float)t / 6.0f);
    } else if (t < 12) {
      float sc = (float)shapes[1] / (float)shapes[lv*2+1];
      ang = (float)xx * sc * powf(100.0f, -(float)(t-6) / 6.0f);
    } else {
      ang = (float)lv * powf(10.0f, -(float)(t-12) / 4.0f);
    }
    cosb[tok*NP_ + t] = cosf(ang);
    sinb[tok*NP_ + t] = sinf(ang);
  }
}

// ---------------- qkv GEMM: (8000x256) @ Wqkv -> q/k/v head-arranged bf16 ----------------
__global__ __launch_bounds__(256) void qkv_gemm(
    const unsigned short* h, const unsigned short* Wt,
    unsigned short* qh, unsigned short* kh, unsigned short* vh) {
  __shared__ unsigned short a_lds[64][264];
  int m0 = blockIdx.y * 64;
  int n0 = blockIdx.x * 128;
  int t = threadIdx.x, lane = t & 63, w = t >> 6;
  int lm = lane & 15, lg = lane >> 4;
  for (int it = 0; it < 8; ++it) {
    int c = it*256 + t;
    int row = c >> 5, off = (c & 31) * 8;
    *(uint4*)&a_lds[row][off] = *(const uint4*)&h[(size_t)(m0+row)*D_ + off];
  }
  __syncthreads();
  f32x4 acc[8];
#pragma unroll
  for (int i = 0; i < 8; ++i) acc[i] = (f32x4){0.f,0.f,0.f,0.f};
#pragma unroll
  for (int ks = 0; ks < 8; ++ks) {
    s16x8 a = *(const s16x8*)&a_lds[w*16 + lm][ks*32 + lg*8];
#pragma unroll
    for (int nt = 0; nt < 8; ++nt) {
      s16x8 bb = *(const s16x8*)&Wt[(size_t)(n0 + nt*16 + lm)*D_ + ks*32 + lg*8];
      acc[nt] = mfma_bf16(a, bb, acc[nt]);
    }
  }
#pragma unroll
  for (int i = 0; i < 4; ++i) {
    int row = w*16 + lg*4 + i;
    int tok = m0 + row;
    int b = tok / 1000, tk = tok - b*1000;
#pragma unroll
    for (int nt = 0; nt < 8; ++nt) {
      int col = n0 + nt*16 + lm;
      int part = col >> 8;
      int within = col & 255;
      int head = within >> 5, d = within & 31;
      unsigned short* dst = part == 0 ? qh : (part == 1 ? kh : vh);
      dst[(size_t)((b*H_ + head)*1000 + tk)*HD_ + d] = f2bf(acc[nt][i]);
    }
  }
}

// ---------------- flash attention per (b,h), rope applied at operand load ----------------
__global__ __launch_bounds__(256) void attn_kernel(
    const unsigned short* qh, const unsigned short* kh, const unsigned short* vh,
    const float* cosb, const float* sinb, unsigned short* obuf) {
  __shared__ unsigned short k_lds[64][40];
  __shared__ unsigned short vt_lds[32][72];
  __shared__ unsigned short p_lds[4][16][72];
  int bh = blockIdx.y;
  int b = bh >> 3, hh = bh & 7;
  int q0 = blockIdx.x * 64;
  int t = threadIdx.x, lane = t & 63, w = t >> 6;
  int lm = lane & 15, lg = lane >> 4;

  int qrow = q0 + w*16 + lm;
  int qtk = qrow < 999 ? qrow : 999;
  int qtokg = b*1000 + qtk;
  s16x8 qf;
  {
    u16x8 raw = *(const u16x8*)&qh[(size_t)(bh*1000 + qtk)*HD_ + lg*8];
    f32x4 c4 = *(const f32x4*)&cosb[(size_t)qtokg*NP_ + lg*4];
    f32x4 s4 = *(const f32x4*)&sinb[(size_t)qtokg*NP_ + lg*4];
#pragma unroll
    for (int m = 0; m < 4; ++m) {
      float t1 = bf2f(raw[2*m]), t2 = bf2f(raw[2*m+1]);
      float e = t1*c4[m] - t2*s4[m];
      float o = t1*s4[m] + t2*c4[m];
      qf[2*m]   = (short)f2bf(e);
      qf[2*m+1] = (short)f2bf(o);
    }
  }

  float m_run[4], l_run[4];
  f32x4 o_acc[2];
#pragma unroll
  for (int i = 0; i < 4; ++i) { m_run[i] = -1e30f; l_run[i] = 0.f; }
  o_acc[0] = (f32x4){0.f,0.f,0.f,0.f};
  o_acc[1] = (f32x4){0.f,0.f,0.f,0.f};

  for (int ch = 0; ch < 16; ++ch) {
    int c0 = ch * 64;
    __syncthreads();
    for (int it = 0; it < 4; ++it) {
      int pi = it*256 + t;
      int key = pi >> 4, pp = pi & 15;
      int tk = c0 + key; tk = tk < 999 ? tk : 999;
      int tokg = b*1000 + tk;
      unsigned raw = *(const unsigned*)&kh[(size_t)(bh*1000 + tk)*HD_ + pp*2];
      float cc = cosb[(size_t)tokg*NP_ + pp], scn = sinb[(size_t)tokg*NP_ + pp];
      float t1 = bf2f((unsigned short)(raw & 0xFFFFu));
      float t2 = bf2f((unsigned short)(raw >> 16));
      float e = t1*cc - t2*scn, od = t1*scn + t2*cc;
      unsigned outp = (unsigned)f2bf(e) | ((unsigned)f2bf(od) << 16);
      *(unsigned*)&k_lds[key][pp*2] = outp;
    }
    for (int it = 0; it < 4; ++it) {
      int e2 = it*256 + t;
      int key = e2 >> 4, dp = e2 & 15;
      int tk = c0 + key; tk = tk < 999 ? tk : 999;
      unsigned raw = *(const unsigned*)&vh[(size_t)(bh*1000 + tk)*HD_ + dp*2];
      vt_lds[dp*2][key]   = (unsigned short)(raw & 0xFFFFu);
      vt_lds[dp*2+1][key] = (unsigned short)(raw >> 16);
    }
    __syncthreads();
    f32x4 sacc[4];
#pragma unroll
    for (int nt = 0; nt < 4; ++nt) {
      sacc[nt] = (f32x4){0.f,0.f,0.f,0.f};
      s16x8 bb = *(const s16x8*)&k_lds[nt*16 + lm][lg*8];
      sacc[nt] = mfma_bf16(qf, bb, sacc[nt]);
    }
    const float scale = 0.17677669529663687f;
#pragma unroll
    for (int nt = 0; nt < 4; ++nt) {
      int col = c0 + nt*16 + lm;
      bool valid = col < 1000;
#pragma unroll
      for (int i = 0; i < 4; ++i) sacc[nt][i] = valid ? sacc[nt][i]*scale : -1e30f;
    }
#pragma unroll
    for (int i = 0; i < 4; ++i) {
      float mx = fmaxf(fmaxf(sacc[0][i], sacc[1][i]), fmaxf(sacc[2][i], sacc[3][i]));
      for (int m = 1; m < 16; m <<= 1) mx = fmaxf(mx, __shfl_xor(mx, m));
      float mn = fmaxf(m_run[i], mx);
      float alpha = __expf(m_run[i] - mn);
      float rsum = 0.f;
#pragma unroll
      for (int nt = 0; nt < 4; ++nt) { float p = __expf(sacc[nt][i] - mn); sacc[nt][i] = p; rsum += p; }
      for (int m = 1; m < 16; m <<= 1) rsum += __shfl_xor(rsum, m);
      l_run[i] = l_run[i]*alpha + rsum;
      m_run[i] = mn;
      o_acc[0][i] *= alpha; o_acc[1][i] *= alpha;
    }
#pragma unroll
    for (int nt = 0; nt < 4; ++nt)
#pragma unroll
      for (int i = 0; i < 4; ++i)
        p_lds[w][lg*4 + i][nt*16 + lm] = f2bf(sacc[nt][i]);
#pragma unroll
    for (int kk = 0; kk < 2; ++kk) {
      s16x8 pf = *(const s16x8*)&p_lds[w][lm][kk*32 + lg*8];
#pragma unroll
      for (int dt = 0; dt < 2; ++dt) {
        s16x8 vf = *(const s16x8*)&vt_lds[dt*16 + lm][kk*32 + lg*8];
        o_acc[dt] = mfma_bf16(pf, vf, o_acc[dt]);
      }
    }
  }
#pragma unroll
  for (int i = 0; i < 4; ++i) {
    int qr = q0 + w*16 + lg*4 + i;
    if (qr < 1000) {
      float innorm = 1.0f / l_run[i];
      int tokg = b*1000 + qr;
#pragma unroll
      for (int dt = 0; dt < 2; ++dt)
        obuf[(size_t)tokg*D_ + hh*HD_ + dt*16 + lm] = f2bf(o_acc[dt][i] * innorm);
    }
  }
}

// ---------------- Wo GEMM + residual -> sa_rows (compact) + slot map ----------------
__global__ __launch_bounds__(256) void wo_scatter(
    const unsigned short* obuf, const unsigned short* Wot,
    const float* queries, const int* idx, float* sa, int* slot_of) {
  __shared__ unsigned short a_lds[64][264];
  int m0 = blockIdx.x * 64;
  int t = threadIdx.x, lane = t & 63, w = t >> 6;
  int lm = lane & 15, lg = lane >> 4;
  for (int it = 0; it < 8; ++it) {
    int c = it*256 + t;
    int row = c >> 5, off = (c & 31) * 8;
    *(uint4*)&a_lds[row][off] = *(const uint4*)&obuf[(size_t)(m0+row)*D_ + off];
  }
  if (t < 64) { int tok = m0 + t; slot_of[idx[tok]] = tok; }
  __syncthreads();
  f32x4 acc[16];
#pragma unroll
  for (int i = 0; i < 16; ++i) acc[i] = (f32x4){0.f,0.f,0.f,0.f};
#pragma unroll
  for (int ks = 0; ks < 8; ++ks) {
    s16x8 a = *(const s16x8*)&a_lds[w*16 + lm][ks*32 + lg*8];
#pragma unroll
    for (int nt = 0; nt < 16; ++nt) {
      s16x8 bb = *(const s16x8*)&Wot[(size_t)(nt*16 + lm)*D_ + ks*32 + lg*8];
      acc[nt] = mfma_bf16(a, bb, acc[nt]);
    }
  }
#pragma unroll
  for (int i = 0; i < 4; ++i) {
    int row = w*16 + lg*4 + i;
    int tok = m0 + row;
    int g = idx[tok];
#pragma unroll
    for (int nt = 0; nt < 16; ++nt) {
      int col = nt*16 + lm;
      sa[(size_t)tok*D_ + col] = queries[(size_t)g*D_ + col] + acc[nt][i];
    }
  }
}

// ---------------- fused LN2 + FFN, writes every out element once ----------------
__global__ __launch_bounds__(512, 4) void ffn_kernel(
    const float* queries, const float* sa, const int* slot_of,
    const unsigned short* W1t, const unsigned short* W2t,
    const float* b1, const float* b2, const float* g2, const float* bb2,
    float* out) {
  __shared__ unsigned short h2_lds[64][264];
  __shared__ unsigned short c1_lds[64][136];
  int m0 = blockIdx.x * 64;
  int t = threadIdx.x, lane = t & 63, w = t >> 6;   // 8 waves
  int lm = lane & 15, lg = lane >> 4;
  // one-pass LN: wave w owns rows w*8 .. w*8+7
  f32x4 g2v  = *(const f32x4*)&g2[lane*4];
  f32x4 bb2v = *(const f32x4*)&bb2[lane*4];
#pragma unroll
  for (int rr = 0; rr < 8; ++rr) {
    int row = w*8 + rr;
    int grow = m0 + row;
    int slot = slot_of[grow];
    const float* xb = (slot >= 0) ? (sa + (size_t)slot * D_) : (queries + (size_t)grow * D_);
    f32x4 x = *(const f32x4*)&xb[lane*4];
    float s1 = x[0]+x[1]+x[2]+x[3];
    float s2 = x[0]*x[0]+x[1]*x[1]+x[2]*x[2]+x[3]*x[3];
    for (int m = 1; m < 64; m <<= 1) { s1 += __shfl_xor(s1, m); s2 += __shfl_xor(s2, m); }
    float mu = s1 * (1.0f/D_);
    float rs = __builtin_amdgcn_rsqf(s2 * (1.0f/D_) - mu*mu + 1e-5f);
    u16x4 hv;
#pragma unroll
    for (int j = 0; j < 4; ++j) hv[j] = f2bf((x[j]-mu)*rs*g2v[j] + bb2v[j]);
    *(u16x4*)&h2_lds[row][lane*4] = hv;
  }
  __syncthreads();
  f32x4 acc2[4][2];
#pragma unroll
  for (int mi = 0; mi < 4; ++mi) { acc2[mi][0] = (f32x4){0.f,0.f,0.f,0.f}; acc2[mi][1] = (f32x4){0.f,0.f,0.f,0.f}; }

  for (int chn = 0; chn < 8; ++chn) {
    int d0 = chn * 128;
    f32x4 acc1[4];
#pragma unroll
    for (int mi = 0; mi < 4; ++mi) acc1[mi] = (f32x4){0.f,0.f,0.f,0.f};
    // GEMM1: wave w owns chunk cols w*16 .. w*16+15
#pragma unroll
    for (int ks = 0; ks < 8; ++ks) {
      s16x8 bb = *(const s16x8*)&W1t[(size_t)(d0 + w*16 + lm)*D_ + ks*32 + lg*8];
#pragma unroll
      for (int mi = 0; mi < 4; ++mi) {
        s16x8 a = *(const s16x8*)&h2_lds[mi*16 + lm][ks*32 + lg*8];
        acc1[mi] = mfma_bf16(a, bb, acc1[mi]);
      }
    }
    // cheap tanh-gelu: th = 1 - 2e/(1+e), e = 2^(-2z*log2e)
    float bias = b1[d0 + w*16 + lm];
#pragma unroll
    for (int mi = 0; mi < 4; ++mi)
#pragma unroll
      for (int i = 0; i < 4; ++i) {
        float xv = acc1[mi][i] + bias;
        float z = 0.7978845608028654f * xv * fmaf(xv*xv, 0.044715f, 1.0f);
        float e = __builtin_amdgcn_exp2f(z * -2.885390081777927f);
        float r = __builtin_amdgcn_rcpf(1.0f + e);
        float th = fmaf(-2.0f*e, r, 1.0f);
        float y = 0.5f * xv;
        y = fmaf(y, th, y);
        c1_lds[mi*16 + lg*4 + i][w*16 + lm] = f2bf(y);
      }
    __syncthreads();
    // GEMM2: wave w owns out cols w*32 .. w*32+31
#pragma unroll
    for (int ks = 0; ks < 4; ++ks) {
      s16x8 a[4];
#pragma unroll
      for (int mi = 0; mi < 4; ++mi) a[mi] = *(const s16x8*)&c1_lds[mi*16 + lm][ks*32 + lg*8];
#pragma unroll
      for (int nj = 0; nj < 2; ++nj) {
        s16x8 bb = *(const s16x8*)&W2t[(size_t)(w*32 + nj*16 + lm)*DFF_ + d0 + ks*32 + lg*8];
#pragma unroll
        for (int mi = 0; mi < 4; ++mi) acc2[mi][nj] = mfma_bf16(a[mi], bb, acc2[mi][nj]);
      }
    }
    __syncthreads();
  }
  float b2v0 = b2[w*32 + lm], b2v1 = b2[w*32 + 16 + lm];
#pragma unroll
  for (int mi = 0; mi < 4; ++mi)
#pragma unroll
    for (int i = 0; i < 4; ++i) {
      int grow = m0 + mi*16 + lg*4 + i;
      int slot = slot_of[grow];
      const float* xb = (slot >= 0) ? (sa + (size_t)slot * D_) : (queries + (size_t)grow * D_);
      size_t rbase = (size_t)grow * D_;
      int c0 = w*32 + lm;
      out[rbase + c0]      = xb[c0]      + acc2[mi][0][i] + b2v0;
      out[rbase + c0 + 16] = xb[c0 + 16] + acc2[mi][1][i] + b2v1;
    }
}

extern "C" void kernel_launch(void* const* d_in, const int* in_sizes, int n_in,
                              void* d_out, int out_size, void* d_ws, size_t ws_size,
                              hipStream_t stream) {
  const float* queries = (const float*)d_in[0];
  const float* sal   = (const float*)d_in[2];
  const float* ele   = (const float*)d_in[3];
  const int*   spat  = (const int*)d_in[4];
  const int*   shapes= (const int*)d_in[6];
  const float* Wqkv  = (const float*)d_in[7];
  const float* Wo    = (const float*)d_in[8];
  const float* ln1g  = (const float*)d_in[9];
  const float* ln1b  = (const float*)d_in[10];
  const float* W1    = (const float*)d_in[11];
  const float* b1    = (const float*)d_in[12];
  const float* W2    = (const float*)d_in[13];
  const float* b2    = (const float*)d_in[14];
  const float* ln2g  = (const float*)d_in[15];
  const float* ln2b  = (const float*)d_in[16];
  float* out = (float*)d_out;

  char* ws = (char*)d_ws;
  size_t off = 0;
  auto alloc = [&](size_t bytes) -> void* {
    void* p = ws + off;
    off = (off + bytes + 255) & ~(size_t)255;
    return p;
  };
  int*            idxb  = (int*)alloc((size_t)NTOK * 4);
  unsigned short* h     = (unsigned short*)alloc((size_t)NTOK * D_ * 2);
  float*          cosb  = (float*)alloc((size_t)NTOK * NP_ * 4);
  float*          sinb  = (float*)alloc((size_t)NTOK * NP_ * 4);
  unsigned short* qh    = (unsigned short*)alloc((size_t)NTOK * D_ * 2);
  unsigned short* kh    = (unsigned short*)alloc((size_t)NTOK * D_ * 2);
  unsigned short* vh    = (unsigned short*)alloc((size_t)NTOK * D_ * 2);
  unsigned short* obuf  = (unsigned short*)alloc((size_t)NTOK * D_ * 2);
  unsigned short* Wqkvt = (unsigned short*)alloc((size_t)768 * 256 * 2);
  unsigned short* Wot   = (unsigned short*)alloc((size_t)256 * 256 * 2);
  unsigned short* W1t   = (unsigned short*)alloc((size_t)1024 * 256 * 2);
  unsigned short* W2t   = (unsigned short*)alloc((size_t)256 * 1024 * 2);
  float*          sa    = (float*)alloc((size_t)NTOK * D_ * 4);
  int*            slot  = (int*)alloc((size_t)NALL * 4);

  hipMemsetAsync(slot, 0xFF, (size_t)NALL * 4, stream);   // -1 everywhere
  transpose_w<<<dim3(768/32, 256/32), 256, 0, stream>>>(Wqkv, Wqkvt, 256, 768);
  transpose_w<<<dim3(256/32, 256/32), 256, 0, stream>>>(Wo,   Wot,   256, 256);
  transpose_w<<<dim3(1024/32, 256/32), 256, 0, stream>>>(W1,  W1t,   256, 1024);
  transpose_w<<<dim3(256/32, 1024/32), 256, 0, stream>>>(W2,  W2t,  1024, 256);
  topk_kernel<<<B_, 1024, 0, stream>>>(ele, sal, idxb);
  gather_ln_rope<<<NTOK, 256, 0, stream>>>(queries, idxb, spat, shapes, ln1g, ln1b, h, cosb, sinb);
  qkv_gemm<<<dim3(6, 125), 256, 0, stream>>>(h, Wqkvt, qh, kh, vh);
  attn_kernel<<<dim3(16, 64), 256, 0, stream>>>(qh, kh, vh, cosb, sinb, obuf);
  wo_scatter<<<125, 256, 0, stream>>>(obuf, Wot, queries, idxb, sa, slot);
  ffn_kernel<<<2048, 512, 0, stream>>>(queries, sa, slot, W1t, W2t, b1, b2, ln2g, ln2b, out);
}

// Round 4
// 485.813 us; speedup vs baseline: 2.9224x; 1.0453x over previous
//
#include <hip/hip_runtime.h>
#include <hip/hip_bf16.h>
#include <math.h>

#define B_   8
#define L_   16384
#define D_   256
#define H_   8
#define DFF_ 1024
#define KSEL 1000
#define NTOK (B_*KSEL)   // 8000
#define NALL (B_*L_)     // 131072
#define HD_  32
#define NP_  16

typedef float f32x4 __attribute__((ext_vector_type(4)));
typedef short s16x8 __attribute__((ext_vector_type(8)));
typedef unsigned short u16x8 __attribute__((ext_vector_type(8)));
typedef unsigned short u16x4 __attribute__((ext_vector_type(4)));

// hardware bf16 convert (fptrunc -> v_cvt_pk_bf16_f32 on gfx950), RNE
static __device__ __forceinline__ unsigned short f2bf(float f) {
  __bf16 b = (__bf16)f;
  return __builtin_bit_cast(unsigned short, b);
}
static __device__ __forceinline__ float bf2f(unsigned short h) {
  return __uint_as_float(((unsigned)h) << 16);
}
static __device__ __forceinline__ f32x4 mfma_bf16(s16x8 a, s16x8 b, f32x4 c) {
  return __builtin_amdgcn_mfma_f32_16x16x32_bf16(a, b, c, 0, 0, 0);
}

// ---------------- weight prep: all four f32 [K][N] -> bf16 [N][K] in one launch ----------------
__global__ __launch_bounds__(256) void transpose_all(
    const float* Wqkv, const float* Wo, const float* W1, const float* W2,
    unsigned short* Wqkvt, unsigned short* Wot, unsigned short* W1t, unsigned short* W2t) {
  __shared__ float tile[32][33];
  int bid = blockIdx.x;
  const float* src; unsigned short* dst; int K, N, tl;
  if (bid < 192)      { src = Wqkv; dst = Wqkvt; K = 256;  N = 768;  tl = bid; }
  else if (bid < 256) { src = Wo;   dst = Wot;   K = 256;  N = 256;  tl = bid - 192; }
  else if (bid < 512) { src = W1;   dst = W1t;   K = 256;  N = 1024; tl = bid - 256; }
  else                { src = W2;   dst = W2t;   K = 1024; N = 256;  tl = bid - 512; }
  int ntx = N >> 5;
  int n0 = (tl % ntx) * 32, k0 = (tl / ntx) * 32;
  int tx = threadIdx.x & 31, ty = threadIdx.x >> 5;   // 32 x 8
#pragma unroll
  for (int r = 0; r < 32; r += 8)
    tile[ty + r][tx] = src[(size_t)(k0 + ty + r) * N + n0 + tx];
  __syncthreads();
#pragma unroll
  for (int r = 0; r < 32; r += 8)
    dst[(size_t)(n0 + ty + r) * K + k0 + tx] = f2bf(tile[tx][ty + r]);
}

// ---------------- per-batch top-K (deterministic, registers + ballot compaction) ----------------
__global__ __launch_bounds__(1024) void topk_kernel(const float* es, const float* ss, int* out_idx) {
  __shared__ int wsum[16];
  __shared__ int chunk_base;
  int b = blockIdx.x;
  int t = threadIdx.x;
  int lane = t & 63, w = t >> 6;
  int base = b * L_;
  unsigned kreg[16];
#pragma unroll
  for (int ci = 0; ci < 16; ++ci) {
    int i = ci * 1024 + t;
    float f = es[base + i] + ss[base + i];
    unsigned u = __float_as_uint(f);
    kreg[ci] = (u & 0x80000000u) ? ~u : (u | 0x80000000u);   // sortable
  }
  // bitwise search: max v with count(>= v) >= K  ->  v = K-th largest key
  unsigned v = 0;
  for (int bit = 31; bit >= 0; --bit) {
    unsigned cand = v | (1u << bit);
    int c = 0;
#pragma unroll
    for (int ci = 0; ci < 16; ++ci) c += (kreg[ci] >= cand) ? 1 : 0;
    for (int m = 1; m < 64; m <<= 1) c += __shfl_xor(c, m);
    if (lane == 0) wsum[w] = c;
    __syncthreads();
    int tot = 0;
#pragma unroll
    for (int j = 0; j < 16; ++j) tot += wsum[j];
    if (tot >= KSEL) v = cand;
    __syncthreads();
  }
  // pass 0: compact indices with key > v; pass 1: fill remainder with key == v (pos<K guard)
  if (t == 0) chunk_base = 0;
  __syncthreads();
  for (int pass = 0; pass < 2; ++pass) {
    for (int ci = 0; ci < 16; ++ci) {
      bool pred = (pass == 0) ? (kreg[ci] > v) : (kreg[ci] == v);
      unsigned long long mask = __ballot(pred);
      if (lane == 0) wsum[w] = __popcll(mask);
      __syncthreads();
      int wbase = chunk_base;
      for (int j = 0; j < w; ++j) wbase += wsum[j];
      if (pred) {
        int pos = wbase + __popcll(mask & ((1ull << lane) - 1ull));
        if (pos < KSEL) out_idx[b * KSEL + pos] = base + ci * 1024 + t;
      }
      __syncthreads();
      if (t == 0) { int tt = 0; for (int j = 0; j < 16; ++j) tt += wsum[j]; chunk_base += tt; }
      __syncthreads();
    }
  }
}

// ---------------- gather + LN1 + rope cos/sin tables ----------------
__global__ __launch_bounds__(256) void gather_ln_rope(
    const float* queries, const int* idx, const int* spat, const int* shapes,
    const float* g1, const float* b1ln, unsigned short* h, float* cosb, float* sinb) {
  int tok = blockIdx.x;
  int t = threadIdx.x;
  int gidx = idx[tok];
  float x = queries[(size_t)gidx * D_ + t];
  float s1 = x, s2 = x * x;
  for (int m = 1; m < 64; m <<= 1) { s1 += __shfl_xor(s1, m); s2 += __shfl_xor(s2, m); }
  __shared__ float p1[4], p2[4];
  int w = t >> 6;
  if ((t & 63) == 0) { p1[w] = s1; p2[w] = s2; }
  __syncthreads();
  float tot  = p1[0] + p1[1] + p1[2] + p1[3];
  float tot2 = p2[0] + p2[1] + p2[2] + p2[3];
  float mu = tot / D_;
  float var = tot2 / D_ - mu * mu;
  float rs = 1.0f / sqrtf(var + 1e-5f);
  h[(size_t)tok * D_ + t] = f2bf((x - mu) * rs * g1[t] + b1ln[t]);
  if (t < NP_) {
    int yy = spat[1*(size_t)NALL + gidx];
    int xx = spat[2*(size_t)NALL + gidx];
    int lv = spat[3*(size_t)NALL + gidx];
    float ang;
    if (t < 6) {
      float sc = (float)shapes[0] / (float)shapes[lv*2+0];
      ang = (float)yy * sc * powf(100.0f, -(float)t / 6.0f);
    } else if (t < 12) {
      float sc = (float)shapes[1] / (float)shapes[lv*2+1];
      ang = (float)xx * sc * powf(100.0f, -(float)(t-6) / 6.0f);
    } else {
      ang = (float)lv * powf(10.0f, -(float)(t-12) / 4.0f);
    }
    cosb[tok*NP_ + t] = cosf(ang);
    sinb[tok*NP_ + t] = sinf(ang);
  }
}

// ---------------- qkv GEMM: (8000x256) @ Wqkv -> q/k/v head-arranged bf16 ----------------
__global__ __launch_bounds__(256) void qkv_gemm(
    const unsigned short* h, const unsigned short* Wt,
    unsigned short* qh, unsigned short* kh, unsigned short* vh) {
  __shared__ unsigned short a_lds[64][264];
  int m0 = blockIdx.y * 64;
  int n0 = blockIdx.x * 128;
  int t = threadIdx.x, lane = t & 63, w = t >> 6;
  int lm = lane & 15, lg = lane >> 4;
  for (int it = 0; it < 8; ++it) {
    int c = it*256 + t;
    int row = c >> 5, off = (c & 31) * 8;
    *(uint4*)&a_lds[row][off] = *(const uint4*)&h[(size_t)(m0+row)*D_ + off];
  }
  __syncthreads();
  f32x4 acc[8];
#pragma unroll
  for (int i = 0; i < 8; ++i) acc[i] = (f32x4){0.f,0.f,0.f,0.f};
#pragma unroll
  for (int ks = 0; ks < 8; ++ks) {
    s16x8 a = *(const s16x8*)&a_lds[w*16 + lm][ks*32 + lg*8];
#pragma unroll
    for (int nt = 0; nt < 8; ++nt) {
      s16x8 bb = *(const s16x8*)&Wt[(size_t)(n0 + nt*16 + lm)*D_ + ks*32 + lg*8];
      acc[nt] = mfma_bf16(a, bb, acc[nt]);
    }
  }
#pragma unroll
  for (int i = 0; i < 4; ++i) {
    int row = w*16 + lg*4 + i;
    int tok = m0 + row;
    int b = tok / 1000, tk = tok - b*1000;
#pragma unroll
    for (int nt = 0; nt < 8; ++nt) {
      int col = n0 + nt*16 + lm;
      int part = col >> 8;
      int within = col & 255;
      int head = within >> 5, d = within & 31;
      unsigned short* dst = part == 0 ? qh : (part == 1 ? kh : vh);
      dst[(size_t)((b*H_ + head)*1000 + tk)*HD_ + d] = f2bf(acc[nt][i]);
    }
  }
}

// ---------------- flash attention per (b,h), rope applied at operand load ----------------
__global__ __launch_bounds__(256) void attn_kernel(
    const unsigned short* qh, const unsigned short* kh, const unsigned short* vh,
    const float* cosb, const float* sinb, unsigned short* obuf) {
  __shared__ unsigned short k_lds[64][40];
  __shared__ unsigned short vt_lds[32][72];
  __shared__ unsigned short p_lds[4][16][72];
  int bh = blockIdx.y;
  int b = bh >> 3, hh = bh & 7;
  int q0 = blockIdx.x * 64;
  int t = threadIdx.x, lane = t & 63, w = t >> 6;
  int lm = lane & 15, lg = lane >> 4;

  int qrow = q0 + w*16 + lm;
  int qtk = qrow < 999 ? qrow : 999;
  int qtokg = b*1000 + qtk;
  s16x8 qf;
  {
    u16x8 raw = *(const u16x8*)&qh[(size_t)(bh*1000 + qtk)*HD_ + lg*8];
    f32x4 c4 = *(const f32x4*)&cosb[(size_t)qtokg*NP_ + lg*4];
    f32x4 s4 = *(const f32x4*)&sinb[(size_t)qtokg*NP_ + lg*4];
#pragma unroll
    for (int m = 0; m < 4; ++m) {
      float t1 = bf2f(raw[2*m]), t2 = bf2f(raw[2*m+1]);
      float e = t1*c4[m] - t2*s4[m];
      float o = t1*s4[m] + t2*c4[m];
      qf[2*m]   = (short)f2bf(e);
      qf[2*m+1] = (short)f2bf(o);
    }
  }

  float m_run[4], l_run[4];
  f32x4 o_acc[2];
#pragma unroll
  for (int i = 0; i < 4; ++i) { m_run[i] = -1e30f; l_run[i] = 0.f; }
  o_acc[0] = (f32x4){0.f,0.f,0.f,0.f};
  o_acc[1] = (f32x4){0.f,0.f,0.f,0.f};

  for (int ch = 0; ch < 16; ++ch) {
    int c0 = ch * 64;
    __syncthreads();
    for (int it = 0; it < 4; ++it) {
      int pi = it*256 + t;
      int key = pi >> 4, pp = pi & 15;
      int tk = c0 + key; tk = tk < 999 ? tk : 999;
      int tokg = b*1000 + tk;
      unsigned raw = *(const unsigned*)&kh[(size_t)(bh*1000 + tk)*HD_ + pp*2];
      float cc = cosb[(size_t)tokg*NP_ + pp], scn = sinb[(size_t)tokg*NP_ + pp];
      float t1 = bf2f((unsigned short)(raw & 0xFFFFu));
      float t2 = bf2f((unsigned short)(raw >> 16));
      float e = t1*cc - t2*scn, od = t1*scn + t2*cc;
      unsigned outp = (unsigned)f2bf(e) | ((unsigned)f2bf(od) << 16);
      *(unsigned*)&k_lds[key][pp*2] = outp;
    }
    for (int it = 0; it < 4; ++it) {
      int e2 = it*256 + t;
      int key = e2 >> 4, dp = e2 & 15;
      int tk = c0 + key; tk = tk < 999 ? tk : 999;
      unsigned raw = *(const unsigned*)&vh[(size_t)(bh*1000 + tk)*HD_ + dp*2];
      vt_lds[dp*2][key]   = (unsigned short)(raw & 0xFFFFu);
      vt_lds[dp*2+1][key] = (unsigned short)(raw >> 16);
    }
    __syncthreads();
    f32x4 sacc[4];
#pragma unroll
    for (int nt = 0; nt < 4; ++nt) {
      sacc[nt] = (f32x4){0.f,0.f,0.f,0.f};
      s16x8 bb = *(const s16x8*)&k_lds[nt*16 + lm][lg*8];
      sacc[nt] = mfma_bf16(qf, bb, sacc[nt]);
    }
    const float scale = 0.17677669529663687f;
#pragma unroll
    for (int nt = 0; nt < 4; ++nt) {
      int col = c0 + nt*16 + lm;
      bool valid = col < 1000;
#pragma unroll
      for (int i = 0; i < 4; ++i) sacc[nt][i] = valid ? sacc[nt][i]*scale : -1e30f;
    }
#pragma unroll
    for (int i = 0; i < 4; ++i) {
      float mx = fmaxf(fmaxf(sacc[0][i], sacc[1][i]), fmaxf(sacc[2][i], sacc[3][i]));
      for (int m = 1; m < 16; m <<= 1) mx = fmaxf(mx, __shfl_xor(mx, m));
      float mn = fmaxf(m_run[i], mx);
      float alpha = __expf(m_run[i] - mn);
      float rsum = 0.f;
#pragma unroll
      for (int nt = 0; nt < 4; ++nt) { float p = __expf(sacc[nt][i] - mn); sacc[nt][i] = p; rsum += p; }
      for (int m = 1; m < 16; m <<= 1) rsum += __shfl_xor(rsum, m);
      l_run[i] = l_run[i]*alpha + rsum;
      m_run[i] = mn;
      o_acc[0][i] *= alpha; o_acc[1][i] *= alpha;
    }
#pragma unroll
    for (int nt = 0; nt < 4; ++nt)
#pragma unroll
      for (int i = 0; i < 4; ++i)
        p_lds[w][lg*4 + i][nt*16 + lm] = f2bf(sacc[nt][i]);
#pragma unroll
    for (int kk = 0; kk < 2; ++kk) {
      s16x8 pf = *(const s16x8*)&p_lds[w][lm][kk*32 + lg*8];
#pragma unroll
      for (int dt = 0; dt < 2; ++dt) {
        s16x8 vf = *(const s16x8*)&vt_lds[dt*16 + lm][kk*32 + lg*8];
        o_acc[dt] = mfma_bf16(pf, vf, o_acc[dt]);
      }
    }
  }
#pragma unroll
  for (int i = 0; i < 4; ++i) {
    int qr = q0 + w*16 + lg*4 + i;
    if (qr < 1000) {
      float innorm = 1.0f / l_run[i];
      int tokg = b*1000 + qr;
#pragma unroll
      for (int dt = 0; dt < 2; ++dt)
        obuf[(size_t)tokg*D_ + hh*HD_ + dt*16 + lm] = f2bf(o_acc[dt][i] * innorm);
    }
  }
}

// ---------------- Wo GEMM + residual -> sa_rows (compact) + slot map ----------------
__global__ __launch_bounds__(256) void wo_scatter(
    const unsigned short* obuf, const unsigned short* Wot,
    const float* queries, const int* idx, float* sa, int* slot_of) {
  __shared__ unsigned short a_lds[64][264];
  int m0 = blockIdx.x * 64;
  int t = threadIdx.x, lane = t & 63, w = t >> 6;
  int lm = lane & 15, lg = lane >> 4;
  for (int it = 0; it < 8; ++it) {
    int c = it*256 + t;
    int row = c >> 5, off = (c & 31) * 8;
    *(uint4*)&a_lds[row][off] = *(const uint4*)&obuf[(size_t)(m0+row)*D_ + off];
  }
  if (t < 64) { int tok = m0 + t; slot_of[idx[tok]] = tok; }
  __syncthreads();
  f32x4 acc[16];
#pragma unroll
  for (int i = 0; i < 16; ++i) acc[i] = (f32x4){0.f,0.f,0.f,0.f};
#pragma unroll
  for (int ks = 0; ks < 8; ++ks) {
    s16x8 a = *(const s16x8*)&a_lds[w*16 + lm][ks*32 + lg*8];
#pragma unroll
    for (int nt = 0; nt < 16; ++nt) {
      s16x8 bb = *(const s16x8*)&Wot[(size_t)(nt*16 + lm)*D_ + ks*32 + lg*8];
      acc[nt] = mfma_bf16(a, bb, acc[nt]);
    }
  }
#pragma unroll
  for (int i = 0; i < 4; ++i) {
    int row = w*16 + lg*4 + i;
    int tok = m0 + row;
    int g = idx[tok];
#pragma unroll
    for (int nt = 0; nt < 16; ++nt) {
      int col = nt*16 + lm;
      sa[(size_t)tok*D_ + col] = queries[(size_t)g*D_ + col] + acc[nt][i];
    }
  }
}

// ---------------- fused LN2 + FFN, register-prefetched W fragments ----------------
__global__ __launch_bounds__(512, 4) void ffn_kernel(
    const float* queries, const float* sa, const int* slot_of,
    const unsigned short* W1t, const unsigned short* W2t,
    const float* b1, const float* b2, const float* g2, const float* bb2,
    float* out) {
  __shared__ unsigned short h2_lds[64][264];
  __shared__ unsigned short c1_lds[64][136];
  int m0 = blockIdx.x * 64;
  int t = threadIdx.x, lane = t & 63, w = t >> 6;   // 8 waves
  int lm = lane & 15, lg = lane >> 4;
  // one-pass LN: wave w owns rows w*8 .. w*8+7
  f32x4 g2v  = *(const f32x4*)&g2[lane*4];
  f32x4 bb2v = *(const f32x4*)&bb2[lane*4];
#pragma unroll
  for (int rr = 0; rr < 8; ++rr) {
    int row = w*8 + rr;
    int grow = m0 + row;
    int slot = slot_of[grow];
    const float* xb = (slot >= 0) ? (sa + (size_t)slot * D_) : (queries + (size_t)grow * D_);
    f32x4 x = *(const f32x4*)&xb[lane*4];
    float s1 = x[0]+x[1]+x[2]+x[3];
    float s2 = x[0]*x[0]+x[1]*x[1]+x[2]*x[2]+x[3]*x[3];
    for (int m = 1; m < 64; m <<= 1) { s1 += __shfl_xor(s1, m); s2 += __shfl_xor(s2, m); }
    float mu = s1 * (1.0f/D_);
    float rs = __builtin_amdgcn_rsqf(s2 * (1.0f/D_) - mu*mu + 1e-5f);
    u16x4 hv;
#pragma unroll
    for (int j = 0; j < 4; ++j) hv[j] = f2bf((x[j]-mu)*rs*g2v[j] + bb2v[j]);
    *(u16x4*)&h2_lds[row][lane*4] = hv;
  }
  __syncthreads();
  f32x4 acc2[4][2];
#pragma unroll
  for (int mi = 0; mi < 4; ++mi) { acc2[mi][0] = (f32x4){0.f,0.f,0.f,0.f}; acc2[mi][1] = (f32x4){0.f,0.f,0.f,0.f}; }

  const unsigned short* w1p = W1t + (size_t)(w*16 + lm) * D_ + lg*8;
  const unsigned short* w2p = W2t + (size_t)(w*32 + lm) * DFF_ + lg*8;

  for (int chn = 0; chn < 8; ++chn) {
    int d0 = chn * 128;
    // prefetch ALL GEMM1 B-fragments for this chunk (8 x 16B, issued back-to-back)
    s16x8 b1f[8];
#pragma unroll
    for (int ks = 0; ks < 8; ++ks)
      b1f[ks] = *(const s16x8*)(w1p + (size_t)d0 * D_ + ks*32);
    f32x4 acc1[4];
#pragma unroll
    for (int mi = 0; mi < 4; ++mi) acc1[mi] = (f32x4){0.f,0.f,0.f,0.f};
    // GEMM1: wave w owns chunk cols w*16 .. w*16+15
#pragma unroll
    for (int ks = 0; ks < 8; ++ks)
#pragma unroll
      for (int mi = 0; mi < 4; ++mi) {
        s16x8 a = *(const s16x8*)&h2_lds[mi*16 + lm][ks*32 + lg*8];
        acc1[mi] = mfma_bf16(a, b1f[ks], acc1[mi]);
      }
    // issue GEMM2 B-fragment loads NOW; latency hides under gelu + barrier
    s16x8 b2f[2][4];
#pragma unroll
    for (int nj = 0; nj < 2; ++nj)
#pragma unroll
      for (int ks = 0; ks < 4; ++ks)
        b2f[nj][ks] = *(const s16x8*)(w2p + (size_t)nj*16*DFF_ + d0 + ks*32);
    // cheap tanh-gelu: th = 1 - 2e/(1+e), e = 2^(-2z*log2e)
    float bias = b1[d0 + w*16 + lm];
#pragma unroll
    for (int mi = 0; mi < 4; ++mi)
#pragma unroll
      for (int i = 0; i < 4; ++i) {
        float xv = acc1[mi][i] + bias;
        float z = 0.7978845608028654f * xv * fmaf(xv*xv, 0.044715f, 1.0f);
        float e = __builtin_amdgcn_exp2f(z * -2.885390081777927f);
        float r = __builtin_amdgcn_rcpf(1.0f + e);
        float th = fmaf(-2.0f*e, r, 1.0f);
        float y = 0.5f * xv;
        y = fmaf(y, th, y);
        c1_lds[mi*16 + lg*4 + i][w*16 + lm] = f2bf(y);
      }
    __syncthreads();
    // GEMM2: wave w owns out cols w*32 .. w*32+31
#pragma unroll
    for (int ks = 0; ks < 4; ++ks) {
      s16x8 a[4];
#pragma unroll
      for (int mi = 0; mi < 4; ++mi) a[mi] = *(const s16x8*)&c1_lds[mi*16 + lm][ks*32 + lg*8];
#pragma unroll
      for (int nj = 0; nj < 2; ++nj)
#pragma unroll
        for (int mi = 0; mi < 4; ++mi) acc2[mi][nj] = mfma_bf16(a[mi], b2f[nj][ks], acc2[mi][nj]);
    }
    __syncthreads();
  }
  float b2v0 = b2[w*32 + lm], b2v1 = b2[w*32 + 16 + lm];
#pragma unroll
  for (int mi = 0; mi < 4; ++mi)
#pragma unroll
    for (int i = 0; i < 4; ++i) {
      int grow = m0 + mi*16 + lg*4 + i;
      int slot = slot_of[grow];
      const float* xb = (slot >= 0) ? (sa + (size_t)slot * D_) : (queries + (size_t)grow * D_);
      size_t rbase = (size_t)grow * D_;
      int c0 = w*32 + lm;
      out[rbase + c0]      = xb[c0]      + acc2[mi][0][i] + b2v0;
      out[rbase + c0 + 16] = xb[c0 + 16] + acc2[mi][1][i] + b2v1;
    }
}

extern "C" void kernel_launch(void* const* d_in, const int* in_sizes, int n_in,
                              void* d_out, int out_size, void* d_ws, size_t ws_size,
                              hipStream_t stream) {
  const float* queries = (const float*)d_in[0];
  const float* sal   = (const float*)d_in[2];
  const float* ele   = (const float*)d_in[3];
  const int*   spat  = (const int*)d_in[4];
  const int*   shapes= (const int*)d_in[6];
  const float* Wqkv  = (const float*)d_in[7];
  const float* Wo    = (const float*)d_in[8];
  const float* ln1g  = (const float*)d_in[9];
  const float* ln1b  = (const float*)d_in[10];
  const float* W1    = (const float*)d_in[11];
  const float* b1    = (const float*)d_in[12];
  const float* W2    = (const float*)d_in[13];
  const float* b2    = (const float*)d_in[14];
  const float* ln2g  = (const float*)d_in[15];
  const float* ln2b  = (const float*)d_in[16];
  float* out = (float*)d_out;

  char* ws = (char*)d_ws;
  size_t off = 0;
  auto alloc = [&](size_t bytes) -> void* {
    void* p = ws + off;
    off = (off + bytes + 255) & ~(size_t)255;
    return p;
  };
  int*            idxb  = (int*)alloc((size_t)NTOK * 4);
  unsigned short* h     = (unsigned short*)alloc((size_t)NTOK * D_ * 2);
  float*          cosb  = (float*)alloc((size_t)NTOK * NP_ * 4);
  float*          sinb  = (float*)alloc((size_t)NTOK * NP_ * 4);
  unsigned short* qh    = (unsigned short*)alloc((size_t)NTOK * D_ * 2);
  unsigned short* kh    = (unsigned short*)alloc((size_t)NTOK * D_ * 2);
  unsigned short* vh    = (unsigned short*)alloc((size_t)NTOK * D_ * 2);
  unsigned short* obuf  = (unsigned short*)alloc((size_t)NTOK * D_ * 2);
  unsigned short* Wqkvt = (unsigned short*)alloc((size_t)768 * 256 * 2);
  unsigned short* Wot   = (unsigned short*)alloc((size_t)256 * 256 * 2);
  unsigned short* W1t   = (unsigned short*)alloc((size_t)1024 * 256 * 2);
  unsigned short* W2t   = (unsigned short*)alloc((size_t)256 * 1024 * 2);
  float*          sa    = (float*)alloc((size_t)NTOK * D_ * 4);
  int*            slot  = (int*)alloc((size_t)NALL * 4);

  hipMemsetAsync(slot, 0xFF, (size_t)NALL * 4, stream);   // -1 everywhere
  transpose_all<<<768, 256, 0, stream>>>(Wqkv, Wo, W1, W2, Wqkvt, Wot, W1t, W2t);
  topk_kernel<<<B_, 1024, 0, stream>>>(ele, sal, idxb);
  gather_ln_rope<<<NTOK, 256, 0, stream>>>(queries, idxb, spat, shapes, ln1g, ln1b, h, cosb, sinb);
  qkv_gemm<<<dim3(6, 125), 256, 0, stream>>>(h, Wqkvt, qh, kh, vh);
  attn_kernel<<<dim3(16, 64), 256, 0, stream>>>(qh, kh, vh, cosb, sinb, obuf);
  wo_scatter<<<125, 256, 0, stream>>>(obuf, Wot, queries, idxb, sa, slot);
  ffn_kernel<<<2048, 512, 0, stream>>>(queries, sa, slot, W1t, W2t, b1, b2, ln2g, ln2b, out);
}